// Round 8
// baseline (201.139 us; speedup 1.0000x reference)
//
#include <hip/hip_runtime.h>
#include <hip/hip_bf16.h>

// MultiBertAttention fp32 I/O, bf16 MFMA internals.
// R17: gemm_out occupancy fix. It was the most starved kernel: 64x128 tile,
//      grid 512 = 2 blocks/CU = 8 waves/CU, single-buffered 2-barrier K-loop
//      -> 16 exposed stage-drains with nothing to hide them (m102's N=1024
//      starvation band). Now 64x64 tiles: grid 1024 = 4 blocks/CU, 16
//      waves/CU, LDS 17.4KB, __launch_bounds__(256,4). Staging/fragment/
//      epilogue patterns identical to verified R16; XCD swizzle bijective on
//      1024 (each XCD: 8 m-panels + full Wo slab = 3MB, L2-resident).
//      prep / gemm_qkvt / attn unchanged from R16.

typedef unsigned short u16;

#define D_MODEL 1024
#define NHEAD 16
#define HDIM 64
#define BATCH 2
#define SEQ 2048
#define MTOT (BATCH * SEQ)  // 4096

#define QSCALE 0.18033688011112042f  // (1/8) * log2(e)

using frag_ab = __attribute__((ext_vector_type(8))) short;  // 8 bf16 (16x16x32 A/B)
using frag_s4 = __attribute__((ext_vector_type(4))) short;  // 4 bf16 (16x16x16 A/B)
using frag_cd = __attribute__((ext_vector_type(4))) float;  // 4 fp32
using f32x2   = __attribute__((ext_vector_type(2))) float;
using u16x8   = __attribute__((ext_vector_type(8))) unsigned short;

__device__ __forceinline__ u16 f2u(float f) {  // RNE fp32->bf16
    union { float f; unsigned int i; } x;
    x.f = f;
    unsigned int r = x.i + 0x7fffu + ((x.i >> 16) & 1u);
    return (u16)(r >> 16);
}
__device__ __forceinline__ unsigned int pkrn(float a, float b) {  // v_cvt_pk_bf16_f32
    union { __hip_bfloat162 h; unsigned int u; } c;
    c.h = __float22bfloat162_rn(float2{a, b});
    return c.u;
}
__device__ __forceinline__ float fexp2(float x) {  // raw v_exp_f32 (inputs bounded)
#if __has_builtin(__builtin_amdgcn_exp2f)
    return __builtin_amdgcn_exp2f(x);
#else
    float r;
    asm("v_exp_f32 %0, %1" : "=v"(r) : "v"(x));
    return r;
#endif
}

// ---------------------------------------------------------------------------
// prep: z<4 -> Wt[z][n][k] = bf16(W_z[k][n]); z==4 -> xb = bf16(x).
// ---------------------------------------------------------------------------
__global__ void prep(const float* __restrict__ W0, const float* __restrict__ W1,
                     const float* __restrict__ W2, const float* __restrict__ W3,
                     const float* __restrict__ X, u16* __restrict__ Wt,
                     u16* __restrict__ Xb) {
    const int z = blockIdx.z;
    const int tx = threadIdx.x, ty = threadIdx.y;
    const int tid = ty * 32 + tx;
    if (z < 4) {
        __shared__ u16 t[32][33];   // t[k_local][n_local]
        const float* W = (z == 0) ? W0 : (z == 1) ? W1 : (z == 2) ? W2 : W3;
        u16* o = Wt + (size_t)z * D_MODEL * D_MODEL;
        int n0 = blockIdx.x * 32, k0 = blockIdx.y * 32;
        #pragma unroll
        for (int i = ty; i < 32; i += 8) t[i][tx] = f2u(W[(size_t)(k0 + i) * D_MODEL + n0 + tx]);
        __syncthreads();
        const int r = tid >> 3, c = tid & 7;   // out row n = r, k-group = c
        ushort4 o4;
        o4.x = t[4 * c + 0][r]; o4.y = t[4 * c + 1][r];
        o4.z = t[4 * c + 2][r]; o4.w = t[4 * c + 3][r];
        *(ushort4*)&o[(size_t)(n0 + r) * D_MODEL + k0 + 4 * c] = o4;
    } else {
        size_t base = ((size_t)(blockIdx.y * 32 + blockIdx.x) * 256 + tid) * 16;
        #pragma unroll
        for (int c = 0; c < 4; ++c) {
            float4 v = *(const float4*)&X[base + c * 4];
            ushort4 o;
            o.x = f2u(v.x); o.y = f2u(v.y); o.z = f2u(v.z); o.w = f2u(v.w);
            *(ushort4*)&Xb[base + c * 4] = o;
        }
    }
}

// ---------------------------------------------------------------------------
// Fused QKV + V^T GEMM, 768 blocks (1D). 128x128 tile, BK=64, global_load_lds.
// XCD swizzle bid=(b&7)*96+(b>>3). Epilogue: C staged to LDS [128][136],
// then 8x ushort8 coalesced stores per thread.
// ---------------------------------------------------------------------------
__launch_bounds__(256, 3)
__global__ void gemm_qkvt(const u16* __restrict__ xb, const u16* __restrict__ Wt,
                          const float* __restrict__ bq, const float* __restrict__ bk,
                          const float* __restrict__ bv, u16* __restrict__ QKw,
                          u16* __restrict__ Vtw) {
    constexpr int BK = 64;
    __shared__ __attribute__((aligned(16))) u16 SM[128 * 136];  // 34.8 KB
    u16* As = SM;              // [128][64]
    u16* Bs = SM + 128 * BK;   // [128][64]

    const int tid = threadIdx.x;
    const int w = tid >> 6;
    const int lane = tid & 63;
    const int lrow = lane & 15, lquad = lane >> 4;
    const size_t WSZ = (size_t)D_MODEL * D_MODEL;
    const size_t TSZ = (size_t)MTOT * D_MODEL;

    const int bid0 = blockIdx.x;
    const int bid = (bid0 & 7) * 96 + (bid0 >> 3);   // XCD-chunked, bijective on 768
    const bool vt = bid >= 512;
    const int z = vt ? 2 : (bid >> 8);
    const int t = vt ? (bid - 512) : (bid & 255);
    const int n0 = vt ? (t & 31) * 128 : (t & 7) * 128;
    const int m0 = vt ? (t >> 5) * 128 : (t >> 3) * 128;
    const u16* Ap = vt ? (Wt + 2 * WSZ) : xb;
    const u16* Bp = vt ? xb : (Wt + (size_t)z * WSZ);
    const float* bias = vt ? bv : (z ? bk : bq);

    frag_cd acc[4][4];
    #pragma unroll
    for (int i = 0; i < 4; i++)
        #pragma unroll
        for (int j = 0; j < 4; j++) acc[i][j] = (frag_cd){0.f, 0.f, 0.f, 0.f};

    const int wm = (w >> 1) * 64, wn = (w & 1) * 64;

    for (int k0 = 0; k0 < D_MODEL; k0 += BK) {
        __syncthreads();
        #pragma unroll
        for (int it = 0; it < 4; ++it) {
            int c = it * 256 + tid;
            int r = c >> 3, c8 = c & 7;
            const u16* ga = Ap + (size_t)(m0 + r) * D_MODEL + k0 + c8 * 8;
            char* la = (char*)As + (it * 256 + w * 64) * 16;
            __builtin_amdgcn_global_load_lds((const __attribute__((address_space(1))) void*)ga,
                                             (__attribute__((address_space(3))) void*)la, 16, 0, 0);
            const u16* gb = Bp + (size_t)(n0 + r) * D_MODEL + k0 + c8 * 8;
            char* lb = (char*)Bs + (it * 256 + w * 64) * 16;
            __builtin_amdgcn_global_load_lds((const __attribute__((address_space(1))) void*)gb,
                                             (__attribute__((address_space(3))) void*)lb, 16, 0, 0);
        }
        __syncthreads();

        #pragma unroll
        for (int kc = 0; kc < 2; ++kc) {
            frag_ab av[4], bvv[4];
            #pragma unroll
            for (int i = 0; i < 4; i++)
                av[i] = *(const frag_ab*)&As[(wm + i * 16 + lrow) * BK + kc * 32 + lquad * 8];
            #pragma unroll
            for (int j = 0; j < 4; j++)
                bvv[j] = *(const frag_ab*)&Bs[(wn + j * 16 + lrow) * BK + kc * 32 + lquad * 8];
            #pragma unroll
            for (int i = 0; i < 4; i++)
                #pragma unroll
                for (int j = 0; j < 4; j++)
                    acc[i][j] = __builtin_amdgcn_mfma_f32_16x16x32_bf16(av[i], bvv[j], acc[i][j], 0, 0, 0);
        }
    }

    // ---- epilogue: stage to LDS [128][136], then coalesced ushort8 stores ----
    const float scale = (!vt && z == 0) ? QSCALE : 1.0f;
    __syncthreads();   // all MFMA reads of As/Bs done before overwrite
    #pragma unroll
    for (int j = 0; j < 4; j++) {
        int col = wn + j * 16 + lrow;
        float bn = vt ? 0.f : bias[n0 + col];
        #pragma unroll
        for (int i = 0; i < 4; i++) {
            #pragma unroll
            for (int rr = 0; rr < 4; ++rr) {
                int row = wm + i * 16 + lquad * 4 + rr;
                float v = vt ? (acc[i][j][rr] + bias[m0 + row])
                             : (acc[i][j][rr] + bn) * scale;
                SM[row * 136 + col] = f2u(v);
            }
        }
    }
    __syncthreads();
    #pragma unroll
    for (int it = 0; it < 8; ++it) {
        int idx = it * 256 + tid;          // 0..2047
        int row = idx >> 4, seg = idx & 15;
        u16x8 v8 = *(const u16x8*)&SM[row * 136 + seg * 8];
        if (!vt) {
            int gm = m0 + row;             // b, s
            int gc = n0 + seg * 8;         // h, d0
            int b = gm >> 11, s = gm & (SEQ - 1);
            int h = gc >> 6, d0 = gc & (HDIM - 1);
            u16* oz = QKw + (size_t)z * TSZ;
            *(u16x8*)&oz[(((size_t)(b * NHEAD + h)) * SEQ + s) * HDIM + d0] = v8;
        } else {
            int gm = m0 + row;             // h, d
            int h = gm >> 6, d = gm & (HDIM - 1);
            int gc = n0 + seg * 8;         // b, s0
            int b = gc >> 11, s0 = gc & (SEQ - 1);
            *(u16x8*)&Vtw[(((size_t)(b * NHEAD + h)) * HDIM + d) * SEQ + s0] = v8;
        }
    }
}

// ---------------------------------------------------------------------------
// Out projection, R17: 64x64 tile, grid 1024 blocks = 4/CU, 16 waves/CU
// (was 2 blocks/CU, 8 waves -> latency-starved). LDS 17.4KB. Wave layout
// 2x2 of 32x32. Epilogue: f32 staged [64][68], coalesced float4 stores.
// XCD swizzle bijective on 1024: each XCD owns 8 m-panels x full Wo slab.
// ---------------------------------------------------------------------------
__launch_bounds__(256, 4)
__global__ void gemm_out(const u16* __restrict__ A, const u16* __restrict__ Wt,
                         const float* __restrict__ bias, float* __restrict__ out) {
    constexpr int BK = 64;
    __shared__ __attribute__((aligned(16))) u16 SM[64 * 68 * 2];  // 17408 B
    u16* As = SM;             // [64][64]
    u16* Bs = SM + 64 * BK;   // [64][64]

    const int tid = threadIdx.x;
    const int w = tid >> 6;
    const int lane = tid & 63;
    const int lrow = lane & 15, lquad = lane >> 4;
    const int L0 = blockIdx.y * 16 + blockIdx.x;     // dispatch-linear 0..1023
    const int L = (L0 & 7) * 128 + (L0 >> 3);        // XCD-chunked, bijective on 1024
    const int m0 = (L >> 4) * 64, n0 = (L & 15) * 64;

    frag_cd acc[2][2];
    #pragma unroll
    for (int i = 0; i < 2; i++)
        #pragma unroll
        for (int j = 0; j < 2; j++) acc[i][j] = (frag_cd){0.f, 0.f, 0.f, 0.f};

    const int wm = (w >> 1) * 32, wn = (w & 1) * 32;

    for (int k0 = 0; k0 < D_MODEL; k0 += BK) {
        __syncthreads();
        #pragma unroll
        for (int it = 0; it < 2; ++it) {
            int c = it * 256 + tid;
            int r = c >> 3, c8 = c & 7;
            const u16* ga = A + (size_t)(m0 + r) * D_MODEL + k0 + c8 * 8;
            char* la = (char*)As + (it * 256 + w * 64) * 16;
            __builtin_amdgcn_global_load_lds((const __attribute__((address_space(1))) void*)ga,
                                             (__attribute__((address_space(3))) void*)la, 16, 0, 0);
            const u16* gb = Wt + (size_t)(n0 + r) * D_MODEL + k0 + c8 * 8;
            char* lb = (char*)Bs + (it * 256 + w * 64) * 16;
            __builtin_amdgcn_global_load_lds((const __attribute__((address_space(1))) void*)gb,
                                             (__attribute__((address_space(3))) void*)lb, 16, 0, 0);
        }
        __syncthreads();

        #pragma unroll
        for (int kc = 0; kc < 2; ++kc) {
            frag_ab av[2], bvv[2];
            #pragma unroll
            for (int i = 0; i < 2; i++)
                av[i] = *(const frag_ab*)&As[(wm + i * 16 + lrow) * BK + kc * 32 + lquad * 8];
            #pragma unroll
            for (int j = 0; j < 2; j++)
                bvv[j] = *(const frag_ab*)&Bs[(wn + j * 16 + lrow) * BK + kc * 32 + lquad * 8];
            #pragma unroll
            for (int i = 0; i < 2; i++)
                #pragma unroll
                for (int j = 0; j < 2; j++)
                    acc[i][j] = __builtin_amdgcn_mfma_f32_16x16x32_bf16(av[i], bvv[j], acc[i][j], 0, 0, 0);
        }
    }

    // ---- epilogue: stage f32 to LDS [64][68], then coalesced float4 stores ----
    float* Tf = (float*)SM;
    __syncthreads();   // all MFMA reads done before overwrite
    #pragma unroll
    for (int j = 0; j < 2; j++) {
        int col = wn + j * 16 + lrow;
        float bvf = bias[n0 + col];
        #pragma unroll
        for (int i = 0; i < 2; i++)
            #pragma unroll
            for (int rr = 0; rr < 4; ++rr) {
                int row = wm + i * 16 + lquad * 4 + rr;
                Tf[row * 68 + col] = acc[i][j][rr] + bvf;
            }
    }
    __syncthreads();
    #pragma unroll
    for (int it = 0; it < 4; ++it) {
        int idx = it * 256 + tid;          // 0..1023
        int row = idx >> 4, seg = idx & 15;
        float4 v = *(const float4*)&Tf[row * 68 + seg * 4];
        *(float4*)&out[(size_t)(m0 + row) * D_MODEL + n0 + seg * 4] = v;
    }
}

// ---------------------------------------------------------------------------
// Attention (R15 structure, unchanged): grid (16,32) = 512 blocks, 512 thr =
// 8 waves (4 qg x 2 kh), each wave owns TWO 16-q fragments. Single-buffered
// 32KB staging (global_load_lds, source-side XOR swizzle); kh-partials
// combined additively via LDS; raw v_exp_f32; setprio; XCD swizzle.
// ---------------------------------------------------------------------------
__launch_bounds__(512, 4)
__global__ void attn_kernel(const u16* __restrict__ Q, const u16* __restrict__ K,
                            const u16* __restrict__ Vt, u16* __restrict__ O) {
    __shared__ __attribute__((aligned(16))) u16 SMEM[17664];  // 35.3 KB
    u16* Ks = SMEM;            // [128 keys][64 d], source-swizzled chunks
    u16* Vs = SMEM + 8192;     // [64 d][128 keys], source-swizzled chunks

    const int tid = threadIdx.x;
    const int w = tid >> 6;           // 8 waves
    const int lane = tid & 63;
    const int lrow = lane & 15, lquad = lane >> 4;
    const int qg = w & 3;             // q-group pair: groups qg, qg+4
    const int kh = w >> 2;            // key half: 0 -> keys [0,64), 1 -> [64,128)

    // XCD-chunked bijective block map: XCD x owns bh = 4x..4x+3, 16 q-tiles each
    const int L = blockIdx.y * 16 + blockIdx.x;      // dispatch-linear 0..511
    const int xcd = L & 7, off = L >> 3;             // off 0..63
    const int bh = xcd * 4 + (off >> 4);             // 0..31
    const int q0 = (off & 15) * 128;

    const size_t base = (size_t)bh * SEQ * HDIM;
    const u16* Qg = Q + base;
    const u16* Kg = K + base;
    const u16* Vg = Vt + base;  // [d][s]

    // Q as B-operand of 16x16x32: lane holds q = lrow, d = kc*32 + lquad*8 + j
    frag_ab qf[2][2];   // [group g][kc]
    #pragma unroll
    for (int g = 0; g < 2; ++g)
        #pragma unroll
        for (int kc = 0; kc < 2; ++kc)
            qf[g][kc] = *(const frag_ab*)&Qg[(size_t)(q0 + (qg + g * 4) * 16 + lrow) * HDIM + kc * 32 + lquad * 8];

    frag_cd accOT[2][4];   // [group][df]: partial O^T, lane q = lrow, d = df*16+lquad*4+i
    #pragma unroll
    for (int g = 0; g < 2; ++g)
        #pragma unroll
        for (int df = 0; df < 4; df++) accOT[g][df] = (frag_cd){0.f, 0.f, 0.f, 0.f};
    f32x2 la0 = (f32x2){0.f, 0.f}, la1 = (f32x2){0.f, 0.f};  // packed rowsum partials

    // ---- hoisted staging addresses (kt-invariant except constant stride) ----
    const int c0 = tid, c1 = 512 + tid;
    const u16* gk0 = Kg + ((c0 >> 3) * HDIM + (((c0 & 7) ^ ((c0 >> 3) & 7)) << 3));
    const u16* gk1 = Kg + ((c1 >> 3) * HDIM + (((c1 & 7) ^ ((c1 >> 3) & 7)) << 3));
    const u16* gv0 = Vg + ((size_t)(c0 >> 4) * SEQ + (((c0 & 15) ^ ((c0 >> 4) & 7)) << 3));
    const u16* gv1 = Vg + ((size_t)(c1 >> 4) * SEQ + (((c1 & 15) ^ ((c1 >> 4) & 7)) << 3));
    char* lk0 = (char*)Ks + (0 * 512 + w * 64) * 16;   // + implicit lane*16
    char* lk1 = (char*)Ks + (1 * 512 + w * 64) * 16;
    char* lv0 = (char*)Vs + (0 * 512 + w * 64) * 16;
    char* lv1 = (char*)Vs + (1 * 512 + w * 64) * 16;

    // ---- hoisted LDS fragment base pointers (kt-invariant) ----
    const u16* kb0 = Ks + (kh * 64 + lrow) * 64 + (((0 + lquad) ^ (lrow & 7)) << 3);
    const u16* kb1 = Ks + (kh * 64 + lrow) * 64 + (((4 + lquad) ^ (lrow & 7)) << 3);
    const u16* vb[4];
    #pragma unroll
    for (int cm = 0; cm < 4; ++cm) {
        const int gc = ((kh * 4 + cm) << 1) + (lquad >> 1);
        vb[cm] = Vs + lrow * 128 + ((gc ^ (lrow & 7)) << 3) + (lquad & 1) * 4;
    }

    for (int kt = 0; kt < SEQ / 128; ++kt) {
        __syncthreads();   // all reads of SMEM done
        __builtin_amdgcn_global_load_lds((const __attribute__((address_space(1))) void*)gk0,
                                         (__attribute__((address_space(3))) void*)lk0, 16, 0, 0);
        __builtin_amdgcn_global_load_lds((const __attribute__((address_space(1))) void*)gk1,
                                         (__attribute__((address_space(3))) void*)lk1, 16, 0, 0);
        __builtin_amdgcn_global_load_lds((const __attribute__((address_space(1))) void*)gv0,
                                         (__attribute__((address_space(3))) void*)lv0, 16, 0, 0);
        __builtin_amdgcn_global_load_lds((const __attribute__((address_space(1))) void*)gv1,
                                         (__attribute__((address_space(3))) void*)lv1, 16, 0, 0);
        gk0 += 128 * HDIM; gk1 += 128 * HDIM;   // next 128-key tile
        gv0 += 128;        gv1 += 128;
        __syncthreads();   // drain vmcnt, tile visible

        // this wave's 64 keys in 4 fragments of 16; each K/V read feeds 2 q-groups
        #pragma unroll
        for (int cm = 0; cm < 4; ++cm) {
            frag_cd sc0 = (frag_cd){0.f, 0.f, 0.f, 0.f};
            frag_cd sc1 = (frag_cd){0.f, 0.f, 0.f, 0.f};
            __builtin_amdgcn_s_setprio(1);
            {
                frag_ab kf0 = *(const frag_ab*)(kb0 + cm * 1024);
                frag_ab kf1 = *(const frag_ab*)(kb1 + cm * 1024);
                sc0 = __builtin_amdgcn_mfma_f32_16x16x32_bf16(kf0, qf[0][0], sc0, 0, 0, 0);
                sc1 = __builtin_amdgcn_mfma_f32_16x16x32_bf16(kf0, qf[1][0], sc1, 0, 0, 0);
                sc0 = __builtin_amdgcn_mfma_f32_16x16x32_bf16(kf1, qf[0][1], sc0, 0, 0, 0);
                sc1 = __builtin_amdgcn_mfma_f32_16x16x32_bf16(kf1, qf[1][1], sc1, 0, 0, 0);
            }
            __builtin_amdgcn_s_setprio(0);

            frag_s4 pk0, pk1;
            {
                float e0 = fexp2(sc0[0]), e1 = fexp2(sc0[1]);
                float e2 = fexp2(sc0[2]), e3 = fexp2(sc0[3]);
                f32x2 a = {e0, e1}, b2 = {e2, e3};
                la0 += a + b2;
                union { frag_s4 s; unsigned int u[2]; } pu;
                pu.u[0] = pkrn(e0, e1);
                pu.u[1] = pkrn(e2, e3);
                pk0 = pu.s;
            }
            {
                float e0 = fexp2(sc1[0]), e1 = fexp2(sc1[1]);
                float e2 = fexp2(sc1[2]), e3 = fexp2(sc1[3]);
                f32x2 a = {e0, e1}, b2 = {e2, e3};
                la1 += a + b2;
                union { frag_s4 s; unsigned int u[2]; } pu;
                pu.u[0] = pkrn(e0, e1);
                pu.u[1] = pkrn(e2, e3);
                pk1 = pu.s;
            }

            // O^T += V^T . P^T : each V fragment feeds both q-groups
            __builtin_amdgcn_s_setprio(1);
            {
                const u16* vp = vb[cm];
                #pragma unroll
                for (int df = 0; df < 4; df++) {
                    frag_s4 vf = *(const frag_s4*)(vp + df * 2048);
                    accOT[0][df] = __builtin_amdgcn_mfma_f32_16x16x16bf16_1k(vf, pk0, accOT[0][df], 0, 0, 0);
                    accOT[1][df] = __builtin_amdgcn_mfma_f32_16x16x16bf16_1k(vf, pk1, accOT[1][df], 0, 0, 0);
                }
            }
            __builtin_amdgcn_s_setprio(0);
        }
    }

    // rowsums: pack-halves + quad reduce (lanes lrow, +16, +32, +48 hold same q)
    float s0 = la0[0] + la0[1];
    s0 += __shfl_xor(s0, 16);
    s0 += __shfl_xor(s0, 32);
    float s1 = la1[0] + la1[1];
    s1 += __shfl_xor(s1, 16);
    s1 += __shfl_xor(s1, 32);

    // combine key-halves additively via LDS (reuse SMEM; stride 68 spreads banks)
    float* comb = (float*)SMEM;               // [128 q][68], 34816 B
    float* lsum = (float*)SMEM + 128 * 68;    // 128 f32
    __syncthreads();   // all tile reads done before overwrite
    if (kh) {
        #pragma unroll
        for (int g = 0; g < 2; ++g) {
            float* crow = comb + ((qg + g * 4) * 16 + lrow) * 68;
            #pragma unroll
            for (int df = 0; df < 4; df++)
                *(float4*)&crow[df * 16 + lquad * 4] =
                    (float4){accOT[g][df][0], accOT[g][df][1], accOT[g][df][2], accOT[g][df][3]};
        }
        if (lquad == 0) {
            lsum[qg * 16 + lrow] = s0;
            lsum[(qg + 4) * 16 + lrow] = s1;
        }
    }
    __syncthreads();
    if (!kh) {
        const int b = bh >> 4, h = bh & (NHEAD - 1);
        #pragma unroll
        for (int g = 0; g < 2; ++g) {
            const float* crow = comb + ((qg + g * 4) * 16 + lrow) * 68;
            #pragma unroll
            for (int df = 0; df < 4; df++) {
                float4 c = *(const float4*)&crow[df * 16 + lquad * 4];
                accOT[g][df][0] += c.x; accOT[g][df][1] += c.y;
                accOT[g][df][2] += c.z; accOT[g][df][3] += c.w;
            }
            float lacc = (g ? s1 : s0) + lsum[(qg + g * 4) * 16 + lrow];

            // epilogue: lane owns one q per group -> single reciprocal; b64 stores
            const int s = q0 + (qg + g * 4) * 16 + lrow;
            const float inv = 1.0f / lacc;
            u16* orow = O + ((size_t)(b * SEQ + s)) * D_MODEL + h * HDIM;
            #pragma unroll
            for (int df = 0; df < 4; df++) {
                union { unsigned int u[2]; ushort4 s4; } o;
                o.u[0] = pkrn(accOT[g][df][0] * inv, accOT[g][df][1] * inv);
                o.u[1] = pkrn(accOT[g][df][2] * inv, accOT[g][df][3] * inv);
                *(ushort4*)&orow[df * 16 + lquad * 4] = o.s4;
            }
        }
    }
}

// ---------------------------------------------------------------------------
// Workspace (u16 elems): xb [0,4M) | Wt 4 slabs [4M,8M) | Q,K [8M,16M)
//                        Vt [16M,20M) | attn-out [20M,24M)   = 48 MB
// ---------------------------------------------------------------------------
extern "C" void kernel_launch(void* const* d_in, const int* in_sizes, int n_in,
                              void* d_out, int out_size, void* d_ws, size_t ws_size,
                              hipStream_t stream) {
    const float* x  = (const float*)d_in[0];
    const float* Wq = (const float*)d_in[1];
    const float* bq = (const float*)d_in[2];
    const float* Wk = (const float*)d_in[3];
    const float* bk = (const float*)d_in[4];
    const float* Wv = (const float*)d_in[5];
    const float* bv = (const float*)d_in[6];
    const float* Wo = (const float*)d_in[7];
    const float* bo = (const float*)d_in[8];

    u16* ws = (u16*)d_ws;
    const size_t WSZ = (size_t)D_MODEL * D_MODEL;    // 1M elems
    const size_t TSZ = (size_t)MTOT * D_MODEL;       // 4M elems
    u16* xb  = ws;
    u16* Wt  = ws + 4 * WSZ;
    u16* QKw = ws + 8 * WSZ;        // Q slab 0, K slab 1
    u16* Vtw = QKw + 2 * TSZ;
    u16* Aw  = Vtw + TSZ;

    prep<<<dim3(32, 32, 5), dim3(32, 8), 0, stream>>>(Wq, Wk, Wv, Wo, x, Wt, xb);
    gemm_qkvt<<<dim3(768), 256, 0, stream>>>(xb, Wt, bq, bk, bv, QKw, Vtw);
    attn_kernel<<<dim3(16, 32), 512, 0, stream>>>(QKw, QKw + TSZ, Vtw, Aw);
    gemm_out<<<dim3(16, 64), 256, 0, stream>>>(Aw, Wt + 3 * WSZ, bo, (float*)d_out);
}

// Round 10
// 199.781 us; speedup vs baseline: 1.0068x; 1.0068x over previous
//
#include <hip/hip_runtime.h>
#include <hip/hip_bf16.h>

// MultiBertAttention fp32 I/O, bf16 MFMA internals.
// R19 = R18 resubmit (previous round died in infra before running; kernel
//      re-audited: LDS budgets, barrier uniformity, swizzle algebra, bounds).
// R18: barrier-count reduction. attn's residual cost (MFMA 35%, LDS ~40%,
//      HBM 4%, occupancy-insensitive) is the lockstep phase structure: 32
//      barriers + 16 vmcnt(0) drains per block. Key-tile doubled to 256
//      (K 256x64 + V 64x256 = 64KB LDS, 2 blocks/CU unchanged): half the
//      barriers/drains, 2x longer compute phases for cross-wave overlap.
//      Same traffic/swizzles/math (cm 0..7). gemm_qkvt: launch_bounds
//      (256,3)->(256,4): 4 blocks/CU (LDS 34.8KB x4 = 139KB fits).
//      prep / gemm_out unchanged from R17.

typedef unsigned short u16;

#define D_MODEL 1024
#define NHEAD 16
#define HDIM 64
#define BATCH 2
#define SEQ 2048
#define MTOT (BATCH * SEQ)  // 4096

#define QSCALE 0.18033688011112042f  // (1/8) * log2(e)

using frag_ab = __attribute__((ext_vector_type(8))) short;  // 8 bf16 (16x16x32 A/B)
using frag_s4 = __attribute__((ext_vector_type(4))) short;  // 4 bf16 (16x16x16 A/B)
using frag_cd = __attribute__((ext_vector_type(4))) float;  // 4 fp32
using f32x2   = __attribute__((ext_vector_type(2))) float;
using u16x8   = __attribute__((ext_vector_type(8))) unsigned short;

__device__ __forceinline__ u16 f2u(float f) {  // RNE fp32->bf16
    union { float f; unsigned int i; } x;
    x.f = f;
    unsigned int r = x.i + 0x7fffu + ((x.i >> 16) & 1u);
    return (u16)(r >> 16);
}
__device__ __forceinline__ unsigned int pkrn(float a, float b) {  // v_cvt_pk_bf16_f32
    union { __hip_bfloat162 h; unsigned int u; } c;
    c.h = __float22bfloat162_rn(float2{a, b});
    return c.u;
}
__device__ __forceinline__ float fexp2(float x) {  // raw v_exp_f32 (inputs bounded)
#if __has_builtin(__builtin_amdgcn_exp2f)
    return __builtin_amdgcn_exp2f(x);
#else
    float r;
    asm("v_exp_f32 %0, %1" : "=v"(r) : "v"(x));
    return r;
#endif
}

// ---------------------------------------------------------------------------
// prep: z<4 -> Wt[z][n][k] = bf16(W_z[k][n]); z==4 -> xb = bf16(x).
// ---------------------------------------------------------------------------
__global__ void prep(const float* __restrict__ W0, const float* __restrict__ W1,
                     const float* __restrict__ W2, const float* __restrict__ W3,
                     const float* __restrict__ X, u16* __restrict__ Wt,
                     u16* __restrict__ Xb) {
    const int z = blockIdx.z;
    const int tx = threadIdx.x, ty = threadIdx.y;
    const int tid = ty * 32 + tx;
    if (z < 4) {
        __shared__ u16 t[32][33];   // t[k_local][n_local]
        const float* W = (z == 0) ? W0 : (z == 1) ? W1 : (z == 2) ? W2 : W3;
        u16* o = Wt + (size_t)z * D_MODEL * D_MODEL;
        int n0 = blockIdx.x * 32, k0 = blockIdx.y * 32;
        #pragma unroll
        for (int i = ty; i < 32; i += 8) t[i][tx] = f2u(W[(size_t)(k0 + i) * D_MODEL + n0 + tx]);
        __syncthreads();
        const int r = tid >> 3, c = tid & 7;   // out row n = r, k-group = c
        ushort4 o4;
        o4.x = t[4 * c + 0][r]; o4.y = t[4 * c + 1][r];
        o4.z = t[4 * c + 2][r]; o4.w = t[4 * c + 3][r];
        *(ushort4*)&o[(size_t)(n0 + r) * D_MODEL + k0 + 4 * c] = o4;
    } else {
        size_t base = ((size_t)(blockIdx.y * 32 + blockIdx.x) * 256 + tid) * 16;
        #pragma unroll
        for (int c = 0; c < 4; ++c) {
            float4 v = *(const float4*)&X[base + c * 4];
            ushort4 o;
            o.x = f2u(v.x); o.y = f2u(v.y); o.z = f2u(v.z); o.w = f2u(v.w);
            *(ushort4*)&Xb[base + c * 4] = o;
        }
    }
}

// ---------------------------------------------------------------------------
// Fused QKV + V^T GEMM, 768 blocks (1D). 128x128 tile, BK=64, global_load_lds.
// XCD swizzle bid=(b&7)*96+(b>>3). 4 blocks/CU. Epilogue: C staged to
// LDS [128][136], then 8x ushort8 coalesced stores per thread.
// ---------------------------------------------------------------------------
__launch_bounds__(256, 4)
__global__ void gemm_qkvt(const u16* __restrict__ xb, const u16* __restrict__ Wt,
                          const float* __restrict__ bq, const float* __restrict__ bk,
                          const float* __restrict__ bv, u16* __restrict__ QKw,
                          u16* __restrict__ Vtw) {
    constexpr int BK = 64;
    __shared__ __attribute__((aligned(16))) u16 SM[128 * 136];  // 34.8 KB
    u16* As = SM;              // [128][64]
    u16* Bs = SM + 128 * BK;   // [128][64]

    const int tid = threadIdx.x;
    const int w = tid >> 6;
    const int lane = tid & 63;
    const int lrow = lane & 15, lquad = lane >> 4;
    const size_t WSZ = (size_t)D_MODEL * D_MODEL;
    const size_t TSZ = (size_t)MTOT * D_MODEL;

    const int bid0 = blockIdx.x;
    const int bid = (bid0 & 7) * 96 + (bid0 >> 3);   // XCD-chunked, bijective on 768
    const bool vt = bid >= 512;
    const int z = vt ? 2 : (bid >> 8);
    const int t = vt ? (bid - 512) : (bid & 255);
    const int n0 = vt ? (t & 31) * 128 : (t & 7) * 128;
    const int m0 = vt ? (t >> 5) * 128 : (t >> 3) * 128;
    const u16* Ap = vt ? (Wt + 2 * WSZ) : xb;
    const u16* Bp = vt ? xb : (Wt + (size_t)z * WSZ);
    const float* bias = vt ? bv : (z ? bk : bq);

    frag_cd acc[4][4];
    #pragma unroll
    for (int i = 0; i < 4; i++)
        #pragma unroll
        for (int j = 0; j < 4; j++) acc[i][j] = (frag_cd){0.f, 0.f, 0.f, 0.f};

    const int wm = (w >> 1) * 64, wn = (w & 1) * 64;

    for (int k0 = 0; k0 < D_MODEL; k0 += BK) {
        __syncthreads();
        #pragma unroll
        for (int it = 0; it < 4; ++it) {
            int c = it * 256 + tid;
            int r = c >> 3, c8 = c & 7;
            const u16* ga = Ap + (size_t)(m0 + r) * D_MODEL + k0 + c8 * 8;
            char* la = (char*)As + (it * 256 + w * 64) * 16;
            __builtin_amdgcn_global_load_lds((const __attribute__((address_space(1))) void*)ga,
                                             (__attribute__((address_space(3))) void*)la, 16, 0, 0);
            const u16* gb = Bp + (size_t)(n0 + r) * D_MODEL + k0 + c8 * 8;
            char* lb = (char*)Bs + (it * 256 + w * 64) * 16;
            __builtin_amdgcn_global_load_lds((const __attribute__((address_space(1))) void*)gb,
                                             (__attribute__((address_space(3))) void*)lb, 16, 0, 0);
        }
        __syncthreads();

        #pragma unroll
        for (int kc = 0; kc < 2; ++kc) {
            frag_ab av[4], bvv[4];
            #pragma unroll
            for (int i = 0; i < 4; i++)
                av[i] = *(const frag_ab*)&As[(wm + i * 16 + lrow) * BK + kc * 32 + lquad * 8];
            #pragma unroll
            for (int j = 0; j < 4; j++)
                bvv[j] = *(const frag_ab*)&Bs[(wn + j * 16 + lrow) * BK + kc * 32 + lquad * 8];
            #pragma unroll
            for (int i = 0; i < 4; i++)
                #pragma unroll
                for (int j = 0; j < 4; j++)
                    acc[i][j] = __builtin_amdgcn_mfma_f32_16x16x32_bf16(av[i], bvv[j], acc[i][j], 0, 0, 0);
        }
    }

    // ---- epilogue: stage to LDS [128][136], then coalesced ushort8 stores ----
    const float scale = (!vt && z == 0) ? QSCALE : 1.0f;
    __syncthreads();   // all MFMA reads of As/Bs done before overwrite
    #pragma unroll
    for (int j = 0; j < 4; j++) {
        int col = wn + j * 16 + lrow;
        float bn = vt ? 0.f : bias[n0 + col];
        #pragma unroll
        for (int i = 0; i < 4; i++) {
            #pragma unroll
            for (int rr = 0; rr < 4; ++rr) {
                int row = wm + i * 16 + lquad * 4 + rr;
                float v = vt ? (acc[i][j][rr] + bias[m0 + row])
                             : (acc[i][j][rr] + bn) * scale;
                SM[row * 136 + col] = f2u(v);
            }
        }
    }
    __syncthreads();
    #pragma unroll
    for (int it = 0; it < 8; ++it) {
        int idx = it * 256 + tid;          // 0..2047
        int row = idx >> 4, seg = idx & 15;
        u16x8 v8 = *(const u16x8*)&SM[row * 136 + seg * 8];
        if (!vt) {
            int gm = m0 + row;             // b, s
            int gc = n0 + seg * 8;         // h, d0
            int b = gm >> 11, s = gm & (SEQ - 1);
            int h = gc >> 6, d0 = gc & (HDIM - 1);
            u16* oz = QKw + (size_t)z * TSZ;
            *(u16x8*)&oz[(((size_t)(b * NHEAD + h)) * SEQ + s) * HDIM + d0] = v8;
        } else {
            int gm = m0 + row;             // h, d
            int h = gm >> 6, d = gm & (HDIM - 1);
            int gc = n0 + seg * 8;         // b, s0
            int b = gc >> 11, s0 = gc & (SEQ - 1);
            *(u16x8*)&Vtw[(((size_t)(b * NHEAD + h)) * HDIM + d) * SEQ + s0] = v8;
        }
    }
}

// ---------------------------------------------------------------------------
// Out projection (R17): 64x64 tile, grid 1024 = 4/CU, LDS 17.4KB.
// ---------------------------------------------------------------------------
__launch_bounds__(256, 4)
__global__ void gemm_out(const u16* __restrict__ A, const u16* __restrict__ Wt,
                         const float* __restrict__ bias, float* __restrict__ out) {
    constexpr int BK = 64;
    __shared__ __attribute__((aligned(16))) u16 SM[64 * 68 * 2];  // 17408 B
    u16* As = SM;             // [64][64]
    u16* Bs = SM + 64 * BK;   // [64][64]

    const int tid = threadIdx.x;
    const int w = tid >> 6;
    const int lane = tid & 63;
    const int lrow = lane & 15, lquad = lane >> 4;
    const int L0 = blockIdx.y * 16 + blockIdx.x;     // dispatch-linear 0..1023
    const int L = (L0 & 7) * 128 + (L0 >> 3);        // XCD-chunked, bijective on 1024
    const int m0 = (L >> 4) * 64, n0 = (L & 15) * 64;

    frag_cd acc[2][2];
    #pragma unroll
    for (int i = 0; i < 2; i++)
        #pragma unroll
        for (int j = 0; j < 2; j++) acc[i][j] = (frag_cd){0.f, 0.f, 0.f, 0.f};

    const int wm = (w >> 1) * 32, wn = (w & 1) * 32;

    for (int k0 = 0; k0 < D_MODEL; k0 += BK) {
        __syncthreads();
        #pragma unroll
        for (int it = 0; it < 2; ++it) {
            int c = it * 256 + tid;
            int r = c >> 3, c8 = c & 7;
            const u16* ga = A + (size_t)(m0 + r) * D_MODEL + k0 + c8 * 8;
            char* la = (char*)As + (it * 256 + w * 64) * 16;
            __builtin_amdgcn_global_load_lds((const __attribute__((address_space(1))) void*)ga,
                                             (__attribute__((address_space(3))) void*)la, 16, 0, 0);
            const u16* gb = Wt + (size_t)(n0 + r) * D_MODEL + k0 + c8 * 8;
            char* lb = (char*)Bs + (it * 256 + w * 64) * 16;
            __builtin_amdgcn_global_load_lds((const __attribute__((address_space(1))) void*)gb,
                                             (__attribute__((address_space(3))) void*)lb, 16, 0, 0);
        }
        __syncthreads();

        #pragma unroll
        for (int kc = 0; kc < 2; ++kc) {
            frag_ab av[2], bvv[2];
            #pragma unroll
            for (int i = 0; i < 2; i++)
                av[i] = *(const frag_ab*)&As[(wm + i * 16 + lrow) * BK + kc * 32 + lquad * 8];
            #pragma unroll
            for (int j = 0; j < 2; j++)
                bvv[j] = *(const frag_ab*)&Bs[(wn + j * 16 + lrow) * BK + kc * 32 + lquad * 8];
            #pragma unroll
            for (int i = 0; i < 2; i++)
                #pragma unroll
                for (int j = 0; j < 2; j++)
                    acc[i][j] = __builtin_amdgcn_mfma_f32_16x16x32_bf16(av[i], bvv[j], acc[i][j], 0, 0, 0);
        }
    }

    // ---- epilogue: stage f32 to LDS [64][68], then coalesced float4 stores ----
    float* Tf = (float*)SM;
    __syncthreads();   // all MFMA reads done before overwrite
    #pragma unroll
    for (int j = 0; j < 2; j++) {
        int col = wn + j * 16 + lrow;
        float bvf = bias[n0 + col];
        #pragma unroll
        for (int i = 0; i < 2; i++)
            #pragma unroll
            for (int rr = 0; rr < 4; ++rr) {
                int row = wm + i * 16 + lquad * 4 + rr;
                Tf[row * 68 + col] = acc[i][j][rr] + bvf;
            }
    }
    __syncthreads();
    #pragma unroll
    for (int it = 0; it < 4; ++it) {
        int idx = it * 256 + tid;          // 0..1023
        int row = idx >> 4, seg = idx & 15;
        float4 v = *(const float4*)&Tf[row * 68 + seg * 4];
        *(float4*)&out[(size_t)(m0 + row) * D_MODEL + n0 + seg * 4] = v;
    }
}

// ---------------------------------------------------------------------------
// Attention, R18: 256-key tiles (K 256x64 + V 64x256 = 64KB LDS) -> 8 loop
// iterations, HALF the barriers/vmcnt drains of R17. Grid (16,32) = 512
// blocks (2/CU, LDS-consistent), 512 thr = 8 waves (4 qg x 2 kh, kh owns
// 128 keys = 8 cm chunks). Each wave owns TWO 16-q fragments. Staging:
// 8 global_load_lds per thread per iter, source-side XOR swizzle (row&7
// algebra unchanged: all row strides are multiples of 8). kh-partials
// combined additively via LDS; raw v_exp_f32; setprio; XCD swizzle.
// ---------------------------------------------------------------------------
__launch_bounds__(512, 4)
__global__ void attn_kernel(const u16* __restrict__ Q, const u16* __restrict__ K,
                            const u16* __restrict__ Vt, u16* __restrict__ O) {
    __shared__ __attribute__((aligned(16))) u16 SMEM[32768];  // 64 KB
    u16* Ks = SMEM;             // [256 keys][64 d], source-swizzled chunks
    u16* Vs = SMEM + 16384;     // [64 d][256 keys], source-swizzled chunks

    const int tid = threadIdx.x;
    const int w = tid >> 6;           // 8 waves
    const int lane = tid & 63;
    const int lrow = lane & 15, lquad = lane >> 4;
    const int qg = w & 3;             // q-group pair: groups qg, qg+4
    const int kh = w >> 2;            // key half: 0 -> keys [0,128), 1 -> [128,256)

    // XCD-chunked bijective block map: XCD x owns bh = 4x..4x+3, 16 q-tiles each
    const int L = blockIdx.y * 16 + blockIdx.x;      // dispatch-linear 0..511
    const int xcd = L & 7, off = L >> 3;             // off 0..63
    const int bh = xcd * 4 + (off >> 4);             // 0..31
    const int q0 = (off & 15) * 128;

    const size_t base = (size_t)bh * SEQ * HDIM;
    const u16* Qg = Q + base;
    const u16* Kg = K + base;
    const u16* Vg = Vt + base;  // [d][s]

    // Q as B-operand of 16x16x32: lane holds q = lrow, d = kc*32 + lquad*8 + j
    frag_ab qf[2][2];   // [group g][kc]
    #pragma unroll
    for (int g = 0; g < 2; ++g)
        #pragma unroll
        for (int kc = 0; kc < 2; ++kc)
            qf[g][kc] = *(const frag_ab*)&Qg[(size_t)(q0 + (qg + g * 4) * 16 + lrow) * HDIM + kc * 32 + lquad * 8];

    frag_cd accOT[2][4];   // [group][df]: partial O^T, lane q = lrow, d = df*16+lquad*4+i
    #pragma unroll
    for (int g = 0; g < 2; ++g)
        #pragma unroll
        for (int df = 0; df < 4; df++) accOT[g][df] = (frag_cd){0.f, 0.f, 0.f, 0.f};
    f32x2 la0 = (f32x2){0.f, 0.f}, la1 = (f32x2){0.f, 0.f};  // packed rowsum partials

    // ---- hoisted staging addresses (kt-invariant except constant stride) ----
    // K tile 256x64 = 2048 chunks: rk=c>>3 (256), ck=c&7; src chunk = ck^(rk&7)
    // V tile 64x256 = 2048 chunks: rv=c>>5 (64), gv=c&31; src chunk = gv^(rv&7)
    const u16* gk[4]; const u16* gv[4]; char* lk[4]; char* lv[4];
    #pragma unroll
    for (int i = 0; i < 4; ++i) {
        const int c = i * 512 + tid;
        gk[i] = Kg + ((c >> 3) * HDIM + (((c & 7) ^ ((c >> 3) & 7)) << 3));
        gv[i] = Vg + ((size_t)(c >> 5) * SEQ + (((c & 31) ^ ((c >> 5) & 7)) << 3));
        lk[i] = (char*)Ks + (i * 512 + w * 64) * 16;   // + implicit lane*16
        lv[i] = (char*)Vs + (i * 512 + w * 64) * 16;
    }

    // ---- hoisted LDS fragment base pointers (kt-invariant) ----
    const u16* kb0 = Ks + (kh * 128 + lrow) * 64 + (((0 + lquad) ^ (lrow & 7)) << 3);
    const u16* kb1 = Ks + (kh * 128 + lrow) * 64 + (((4 + lquad) ^ (lrow & 7)) << 3);
    const u16* vb[8];
    #pragma unroll
    for (int cm = 0; cm < 8; ++cm) {
        const int gc = ((kh * 8 + cm) << 1) + (lquad >> 1);   // 0..31
        vb[cm] = Vs + lrow * 256 + ((gc ^ (lrow & 7)) << 3) + (lquad & 1) * 4;
    }

    for (int kt = 0; kt < SEQ / 256; ++kt) {
        __syncthreads();   // all reads of SMEM done
        #pragma unroll
        for (int i = 0; i < 4; ++i) {
            __builtin_amdgcn_global_load_lds((const __attribute__((address_space(1))) void*)gk[i],
                                             (__attribute__((address_space(3))) void*)lk[i], 16, 0, 0);
            __builtin_amdgcn_global_load_lds((const __attribute__((address_space(1))) void*)gv[i],
                                             (__attribute__((address_space(3))) void*)lv[i], 16, 0, 0);
            gk[i] += 256 * HDIM;   // next 256-key tile
            gv[i] += 256;
        }
        __syncthreads();   // drain vmcnt, tile visible

        // this wave's 128 keys in 8 fragments of 16; each K/V read feeds 2 q-groups
        #pragma unroll
        for (int cm = 0; cm < 8; ++cm) {
            frag_cd sc0 = (frag_cd){0.f, 0.f, 0.f, 0.f};
            frag_cd sc1 = (frag_cd){0.f, 0.f, 0.f, 0.f};
            __builtin_amdgcn_s_setprio(1);
            {
                frag_ab kf0 = *(const frag_ab*)(kb0 + cm * 1024);
                frag_ab kf1 = *(const frag_ab*)(kb1 + cm * 1024);
                sc0 = __builtin_amdgcn_mfma_f32_16x16x32_bf16(kf0, qf[0][0], sc0, 0, 0, 0);
                sc1 = __builtin_amdgcn_mfma_f32_16x16x32_bf16(kf0, qf[1][0], sc1, 0, 0, 0);
                sc0 = __builtin_amdgcn_mfma_f32_16x16x32_bf16(kf1, qf[0][1], sc0, 0, 0, 0);
                sc1 = __builtin_amdgcn_mfma_f32_16x16x32_bf16(kf1, qf[1][1], sc1, 0, 0, 0);
            }
            __builtin_amdgcn_s_setprio(0);

            frag_s4 pk0, pk1;
            {
                float e0 = fexp2(sc0[0]), e1 = fexp2(sc0[1]);
                float e2 = fexp2(sc0[2]), e3 = fexp2(sc0[3]);
                f32x2 a = {e0, e1}, b2 = {e2, e3};
                la0 += a + b2;
                union { frag_s4 s; unsigned int u[2]; } pu;
                pu.u[0] = pkrn(e0, e1);
                pu.u[1] = pkrn(e2, e3);
                pk0 = pu.s;
            }
            {
                float e0 = fexp2(sc1[0]), e1 = fexp2(sc1[1]);
                float e2 = fexp2(sc1[2]), e3 = fexp2(sc1[3]);
                f32x2 a = {e0, e1}, b2 = {e2, e3};
                la1 += a + b2;
                union { frag_s4 s; unsigned int u[2]; } pu;
                pu.u[0] = pkrn(e0, e1);
                pu.u[1] = pkrn(e2, e3);
                pk1 = pu.s;
            }

            // O^T += V^T . P^T : each V fragment feeds both q-groups
            __builtin_amdgcn_s_setprio(1);
            {
                const u16* vp = vb[cm];
                #pragma unroll
                for (int df = 0; df < 4; df++) {
                    frag_s4 vf = *(const frag_s4*)(vp + df * 16 * 256);
                    accOT[0][df] = __builtin_amdgcn_mfma_f32_16x16x16bf16_1k(vf, pk0, accOT[0][df], 0, 0, 0);
                    accOT[1][df] = __builtin_amdgcn_mfma_f32_16x16x16bf16_1k(vf, pk1, accOT[1][df], 0, 0, 0);
                }
            }
            __builtin_amdgcn_s_setprio(0);
        }
    }

    // rowsums: pack-halves + quad reduce (lanes lrow, +16, +32, +48 hold same q)
    float s0 = la0[0] + la0[1];
    s0 += __shfl_xor(s0, 16);
    s0 += __shfl_xor(s0, 32);
    float s1 = la1[0] + la1[1];
    s1 += __shfl_xor(s1, 16);
    s1 += __shfl_xor(s1, 32);

    // combine key-halves additively via LDS (reuse SMEM; stride 68 spreads banks)
    float* comb = (float*)SMEM;               // [128 q][68], 34816 B
    float* lsum = (float*)SMEM + 128 * 68;    // 128 f32
    __syncthreads();   // all tile reads done before overwrite
    if (kh) {
        #pragma unroll
        for (int g = 0; g < 2; ++g) {
            float* crow = comb + ((qg + g * 4) * 16 + lrow) * 68;
            #pragma unroll
            for (int df = 0; df < 4; df++)
                *(float4*)&crow[df * 16 + lquad * 4] =
                    (float4){accOT[g][df][0], accOT[g][df][1], accOT[g][df][2], accOT[g][df][3]};
        }
        if (lquad == 0) {
            lsum[qg * 16 + lrow] = s0;
            lsum[(qg + 4) * 16 + lrow] = s1;
        }
    }
    __syncthreads();
    if (!kh) {
        const int b = bh >> 4, h = bh & (NHEAD - 1);
        #pragma unroll
        for (int g = 0; g < 2; ++g) {
            const float* crow = comb + ((qg + g * 4) * 16 + lrow) * 68;
            #pragma unroll
            for (int df = 0; df < 4; df++) {
                float4 c = *(const float4*)&crow[df * 16 + lquad * 4];
                accOT[g][df][0] += c.x; accOT[g][df][1] += c.y;
                accOT[g][df][2] += c.z; accOT[g][df][3] += c.w;
            }
            float lacc = (g ? s1 : s0) + lsum[(qg + g * 4) * 16 + lrow];

            // epilogue: lane owns one q per group -> single reciprocal; b64 stores
            const int s = q0 + (qg + g * 4) * 16 + lrow;
            const float inv = 1.0f / lacc;
            u16* orow = O + ((size_t)(b * SEQ + s)) * D_MODEL + h * HDIM;
            #pragma unroll
            for (int df = 0; df < 4; df++) {
                union { unsigned int u[2]; ushort4 s4; } o;
                o.u[0] = pkrn(accOT[g][df][0] * inv, accOT[g][df][1] * inv);
                o.u[1] = pkrn(accOT[g][df][2] * inv, accOT[g][df][3] * inv);
                *(ushort4*)&orow[df * 16 + lquad * 4] = o.s4;
            }
        }
    }
}

// ---------------------------------------------------------------------------
// Workspace (u16 elems): xb [0,4M) | Wt 4 slabs [4M,8M) | Q,K [8M,16M)
//                        Vt [16M,20M) | attn-out [20M,24M)   = 48 MB
// ---------------------------------------------------------------------------
extern "C" void kernel_launch(void* const* d_in, const int* in_sizes, int n_in,
                              void* d_out, int out_size, void* d_ws, size_t ws_size,
                              hipStream_t stream) {
    const float* x  = (const float*)d_in[0];
    const float* Wq = (const float*)d_in[1];
    const float* bq = (const float*)d_in[2];
    const float* Wk = (const float*)d_in[3];
    const float* bk = (const float*)d_in[4];
    const float* Wv = (const float*)d_in[5];
    const float* bv = (const float*)d_in[6];
    const float* Wo = (const float*)d_in[7];
    const float* bo = (const float*)d_in[8];

    u16* ws = (u16*)d_ws;
    const size_t WSZ = (size_t)D_MODEL * D_MODEL;    // 1M elems
    const size_t TSZ = (size_t)MTOT * D_MODEL;       // 4M elems
    u16* xb  = ws;
    u16* Wt  = ws + 4 * WSZ;
    u16* QKw = ws + 8 * WSZ;        // Q slab 0, K slab 1
    u16* Vtw = QKw + 2 * TSZ;
    u16* Aw  = Vtw + TSZ;

    prep<<<dim3(32, 32, 5), dim3(32, 8), 0, stream>>>(Wq, Wk, Wv, Wo, x, Wt, xb);
    gemm_qkvt<<<dim3(768), 256, 0, stream>>>(xb, Wt, bq, bk, bv, QKw, Vtw);
    attn_kernel<<<dim3(16, 32), 512, 0, stream>>>(QKw, QKw + TSZ, Vtw, Aw);
    gemm_out<<<dim3(16, 64), 256, 0, stream>>>(Aw, Wt + 3 * WSZ, bo, (float*)d_out);
}

// Round 11
// 196.867 us; speedup vs baseline: 1.0217x; 1.0148x over previous
//
#include <hip/hip_runtime.h>
#include <hip/hip_bf16.h>

// MultiBertAttention fp32 I/O, bf16 MFMA internals.
// R20: PV at full MFMA rate. PV used mfma_16x16x16bf16_1k (legacy half-K) ->
//      64 MFMA/tile/wave; gfx950's 16x16x32 does 2x FLOP/inst at same issue
//      cost. Enabler (zero extra instructions): permute K-tile rows fed to
//      QK's A-operand so S^T lands directly in the K=32 B-operand layout:
//      QK pair sub0 covers keys {8q+0..3}, sub1 {8q+4..7} (row = 8*(lrow>>2)
//      + (lrow&3) [+4]); then lane lquad holds keys 8*lquad+j, j=0..7 ->
//      pb = {pk(sub0), pk(sub1)} feeds mfma_16x16x32 directly. V reads become
//      16x b128 (same DS cycles as 32x b64). QK/exp/rowsum/staging/epilogue
//      byte-identical in cost. prep / gemm_qkvt / gemm_out unchanged (R18).

typedef unsigned short u16;

#define D_MODEL 1024
#define NHEAD 16
#define HDIM 64
#define BATCH 2
#define SEQ 2048
#define MTOT (BATCH * SEQ)  // 4096

#define QSCALE 0.18033688011112042f  // (1/8) * log2(e)

using frag_ab = __attribute__((ext_vector_type(8))) short;  // 8 bf16 (16x16x32 A/B)
using frag_s4 = __attribute__((ext_vector_type(4))) short;  // 4 bf16 (16x16x16 A/B)
using frag_cd = __attribute__((ext_vector_type(4))) float;  // 4 fp32
using f32x2   = __attribute__((ext_vector_type(2))) float;
using u16x8   = __attribute__((ext_vector_type(8))) unsigned short;

__device__ __forceinline__ u16 f2u(float f) {  // RNE fp32->bf16
    union { float f; unsigned int i; } x;
    x.f = f;
    unsigned int r = x.i + 0x7fffu + ((x.i >> 16) & 1u);
    return (u16)(r >> 16);
}
__device__ __forceinline__ unsigned int pkrn(float a, float b) {  // v_cvt_pk_bf16_f32
    union { __hip_bfloat162 h; unsigned int u; } c;
    c.h = __float22bfloat162_rn(float2{a, b});
    return c.u;
}
__device__ __forceinline__ float fexp2(float x) {  // raw v_exp_f32 (inputs bounded)
#if __has_builtin(__builtin_amdgcn_exp2f)
    return __builtin_amdgcn_exp2f(x);
#else
    float r;
    asm("v_exp_f32 %0, %1" : "=v"(r) : "v"(x));
    return r;
#endif
}

// ---------------------------------------------------------------------------
// prep: z<4 -> Wt[z][n][k] = bf16(W_z[k][n]); z==4 -> xb = bf16(x).
// ---------------------------------------------------------------------------
__global__ void prep(const float* __restrict__ W0, const float* __restrict__ W1,
                     const float* __restrict__ W2, const float* __restrict__ W3,
                     const float* __restrict__ X, u16* __restrict__ Wt,
                     u16* __restrict__ Xb) {
    const int z = blockIdx.z;
    const int tx = threadIdx.x, ty = threadIdx.y;
    const int tid = ty * 32 + tx;
    if (z < 4) {
        __shared__ u16 t[32][33];   // t[k_local][n_local]
        const float* W = (z == 0) ? W0 : (z == 1) ? W1 : (z == 2) ? W2 : W3;
        u16* o = Wt + (size_t)z * D_MODEL * D_MODEL;
        int n0 = blockIdx.x * 32, k0 = blockIdx.y * 32;
        #pragma unroll
        for (int i = ty; i < 32; i += 8) t[i][tx] = f2u(W[(size_t)(k0 + i) * D_MODEL + n0 + tx]);
        __syncthreads();
        const int r = tid >> 3, c = tid & 7;   // out row n = r, k-group = c
        ushort4 o4;
        o4.x = t[4 * c + 0][r]; o4.y = t[4 * c + 1][r];
        o4.z = t[4 * c + 2][r]; o4.w = t[4 * c + 3][r];
        *(ushort4*)&o[(size_t)(n0 + r) * D_MODEL + k0 + 4 * c] = o4;
    } else {
        size_t base = ((size_t)(blockIdx.y * 32 + blockIdx.x) * 256 + tid) * 16;
        #pragma unroll
        for (int c = 0; c < 4; ++c) {
            float4 v = *(const float4*)&X[base + c * 4];
            ushort4 o;
            o.x = f2u(v.x); o.y = f2u(v.y); o.z = f2u(v.z); o.w = f2u(v.w);
            *(ushort4*)&Xb[base + c * 4] = o;
        }
    }
}

// ---------------------------------------------------------------------------
// Fused QKV + V^T GEMM, 768 blocks (1D). 128x128 tile, BK=64, global_load_lds.
// XCD swizzle bid=(b&7)*96+(b>>3). 4 blocks/CU. Epilogue: C staged to
// LDS [128][136], then 8x ushort8 coalesced stores per thread.
// ---------------------------------------------------------------------------
__launch_bounds__(256, 4)
__global__ void gemm_qkvt(const u16* __restrict__ xb, const u16* __restrict__ Wt,
                          const float* __restrict__ bq, const float* __restrict__ bk,
                          const float* __restrict__ bv, u16* __restrict__ QKw,
                          u16* __restrict__ Vtw) {
    constexpr int BK = 64;
    __shared__ __attribute__((aligned(16))) u16 SM[128 * 136];  // 34.8 KB
    u16* As = SM;              // [128][64]
    u16* Bs = SM + 128 * BK;   // [128][64]

    const int tid = threadIdx.x;
    const int w = tid >> 6;
    const int lane = tid & 63;
    const int lrow = lane & 15, lquad = lane >> 4;
    const size_t WSZ = (size_t)D_MODEL * D_MODEL;
    const size_t TSZ = (size_t)MTOT * D_MODEL;

    const int bid0 = blockIdx.x;
    const int bid = (bid0 & 7) * 96 + (bid0 >> 3);   // XCD-chunked, bijective on 768
    const bool vt = bid >= 512;
    const int z = vt ? 2 : (bid >> 8);
    const int t = vt ? (bid - 512) : (bid & 255);
    const int n0 = vt ? (t & 31) * 128 : (t & 7) * 128;
    const int m0 = vt ? (t >> 5) * 128 : (t >> 3) * 128;
    const u16* Ap = vt ? (Wt + 2 * WSZ) : xb;
    const u16* Bp = vt ? xb : (Wt + (size_t)z * WSZ);
    const float* bias = vt ? bv : (z ? bk : bq);

    frag_cd acc[4][4];
    #pragma unroll
    for (int i = 0; i < 4; i++)
        #pragma unroll
        for (int j = 0; j < 4; j++) acc[i][j] = (frag_cd){0.f, 0.f, 0.f, 0.f};

    const int wm = (w >> 1) * 64, wn = (w & 1) * 64;

    for (int k0 = 0; k0 < D_MODEL; k0 += BK) {
        __syncthreads();
        #pragma unroll
        for (int it = 0; it < 4; ++it) {
            int c = it * 256 + tid;
            int r = c >> 3, c8 = c & 7;
            const u16* ga = Ap + (size_t)(m0 + r) * D_MODEL + k0 + c8 * 8;
            char* la = (char*)As + (it * 256 + w * 64) * 16;
            __builtin_amdgcn_global_load_lds((const __attribute__((address_space(1))) void*)ga,
                                             (__attribute__((address_space(3))) void*)la, 16, 0, 0);
            const u16* gb = Bp + (size_t)(n0 + r) * D_MODEL + k0 + c8 * 8;
            char* lb = (char*)Bs + (it * 256 + w * 64) * 16;
            __builtin_amdgcn_global_load_lds((const __attribute__((address_space(1))) void*)gb,
                                             (__attribute__((address_space(3))) void*)lb, 16, 0, 0);
        }
        __syncthreads();

        #pragma unroll
        for (int kc = 0; kc < 2; ++kc) {
            frag_ab av[4], bvv[4];
            #pragma unroll
            for (int i = 0; i < 4; i++)
                av[i] = *(const frag_ab*)&As[(wm + i * 16 + lrow) * BK + kc * 32 + lquad * 8];
            #pragma unroll
            for (int j = 0; j < 4; j++)
                bvv[j] = *(const frag_ab*)&Bs[(wn + j * 16 + lrow) * BK + kc * 32 + lquad * 8];
            #pragma unroll
            for (int i = 0; i < 4; i++)
                #pragma unroll
                for (int j = 0; j < 4; j++)
                    acc[i][j] = __builtin_amdgcn_mfma_f32_16x16x32_bf16(av[i], bvv[j], acc[i][j], 0, 0, 0);
        }
    }

    // ---- epilogue: stage to LDS [128][136], then coalesced ushort8 stores ----
    const float scale = (!vt && z == 0) ? QSCALE : 1.0f;
    __syncthreads();   // all MFMA reads of As/Bs done before overwrite
    #pragma unroll
    for (int j = 0; j < 4; j++) {
        int col = wn + j * 16 + lrow;
        float bn = vt ? 0.f : bias[n0 + col];
        #pragma unroll
        for (int i = 0; i < 4; i++) {
            #pragma unroll
            for (int rr = 0; rr < 4; ++rr) {
                int row = wm + i * 16 + lquad * 4 + rr;
                float v = vt ? (acc[i][j][rr] + bias[m0 + row])
                             : (acc[i][j][rr] + bn) * scale;
                SM[row * 136 + col] = f2u(v);
            }
        }
    }
    __syncthreads();
    #pragma unroll
    for (int it = 0; it < 8; ++it) {
        int idx = it * 256 + tid;          // 0..2047
        int row = idx >> 4, seg = idx & 15;
        u16x8 v8 = *(const u16x8*)&SM[row * 136 + seg * 8];
        if (!vt) {
            int gm = m0 + row;             // b, s
            int gc = n0 + seg * 8;         // h, d0
            int b = gm >> 11, s = gm & (SEQ - 1);
            int h = gc >> 6, d0 = gc & (HDIM - 1);
            u16* oz = QKw + (size_t)z * TSZ;
            *(u16x8*)&oz[(((size_t)(b * NHEAD + h)) * SEQ + s) * HDIM + d0] = v8;
        } else {
            int gm = m0 + row;             // h, d
            int h = gm >> 6, d = gm & (HDIM - 1);
            int gc = n0 + seg * 8;         // b, s0
            int b = gc >> 11, s0 = gc & (SEQ - 1);
            *(u16x8*)&Vtw[(((size_t)(b * NHEAD + h)) * HDIM + d) * SEQ + s0] = v8;
        }
    }
}

// ---------------------------------------------------------------------------
// Out projection (R17): 64x64 tile, grid 1024 = 4/CU, LDS 17.4KB.
// ---------------------------------------------------------------------------
__launch_bounds__(256, 4)
__global__ void gemm_out(const u16* __restrict__ A, const u16* __restrict__ Wt,
                         const float* __restrict__ bias, float* __restrict__ out) {
    constexpr int BK = 64;
    __shared__ __attribute__((aligned(16))) u16 SM[64 * 68 * 2];  // 17408 B
    u16* As = SM;             // [64][64]
    u16* Bs = SM + 64 * BK;   // [64][64]

    const int tid = threadIdx.x;
    const int w = tid >> 6;
    const int lane = tid & 63;
    const int lrow = lane & 15, lquad = lane >> 4;
    const int L0 = blockIdx.y * 16 + blockIdx.x;     // dispatch-linear 0..1023
    const int L = (L0 & 7) * 128 + (L0 >> 3);        // XCD-chunked, bijective on 1024
    const int m0 = (L >> 4) * 64, n0 = (L & 15) * 64;

    frag_cd acc[2][2];
    #pragma unroll
    for (int i = 0; i < 2; i++)
        #pragma unroll
        for (int j = 0; j < 2; j++) acc[i][j] = (frag_cd){0.f, 0.f, 0.f, 0.f};

    const int wm = (w >> 1) * 32, wn = (w & 1) * 32;

    for (int k0 = 0; k0 < D_MODEL; k0 += BK) {
        __syncthreads();
        #pragma unroll
        for (int it = 0; it < 2; ++it) {
            int c = it * 256 + tid;
            int r = c >> 3, c8 = c & 7;
            const u16* ga = A + (size_t)(m0 + r) * D_MODEL + k0 + c8 * 8;
            char* la = (char*)As + (it * 256 + w * 64) * 16;
            __builtin_amdgcn_global_load_lds((const __attribute__((address_space(1))) void*)ga,
                                             (__attribute__((address_space(3))) void*)la, 16, 0, 0);
            const u16* gb = Wt + (size_t)(n0 + r) * D_MODEL + k0 + c8 * 8;
            char* lb = (char*)Bs + (it * 256 + w * 64) * 16;
            __builtin_amdgcn_global_load_lds((const __attribute__((address_space(1))) void*)gb,
                                             (__attribute__((address_space(3))) void*)lb, 16, 0, 0);
        }
        __syncthreads();

        #pragma unroll
        for (int kc = 0; kc < 2; ++kc) {
            frag_ab av[2], bvv[2];
            #pragma unroll
            for (int i = 0; i < 2; i++)
                av[i] = *(const frag_ab*)&As[(wm + i * 16 + lrow) * BK + kc * 32 + lquad * 8];
            #pragma unroll
            for (int j = 0; j < 2; j++)
                bvv[j] = *(const frag_ab*)&Bs[(wn + j * 16 + lrow) * BK + kc * 32 + lquad * 8];
            #pragma unroll
            for (int i = 0; i < 2; i++)
                #pragma unroll
                for (int j = 0; j < 2; j++)
                    acc[i][j] = __builtin_amdgcn_mfma_f32_16x16x32_bf16(av[i], bvv[j], acc[i][j], 0, 0, 0);
        }
    }

    // ---- epilogue: stage f32 to LDS [64][68], then coalesced float4 stores ----
    float* Tf = (float*)SM;
    __syncthreads();   // all MFMA reads done before overwrite
    #pragma unroll
    for (int j = 0; j < 2; j++) {
        int col = wn + j * 16 + lrow;
        float bvf = bias[n0 + col];
        #pragma unroll
        for (int i = 0; i < 2; i++)
            #pragma unroll
            for (int rr = 0; rr < 4; ++rr) {
                int row = wm + i * 16 + lquad * 4 + rr;
                Tf[row * 68 + col] = acc[i][j][rr] + bvf;
            }
    }
    __syncthreads();
    #pragma unroll
    for (int it = 0; it < 4; ++it) {
        int idx = it * 256 + tid;          // 0..1023
        int row = idx >> 4, seg = idx & 15;
        float4 v = *(const float4*)&Tf[row * 68 + seg * 4];
        *(float4*)&out[(size_t)(m0 + row) * D_MODEL + n0 + seg * 4] = v;
    }
}

// ---------------------------------------------------------------------------
// Attention, R20: 256-key tiles, 8 iters; PV at K=32 full rate. Grid (16,32)
// = 512 blocks (2/CU), 512 thr = 8 waves (4 qg x 2 kh, kh owns 128 keys =
// 4 pairs of 32). QK covers interleaved key rows (sub0: 8q+0..3, sub1:
// 8q+4..7) so P lands in 16x16x32 B-operand order; PV = 8 MFMA(K=32)/pair.
// Staging/swizzles/kh-combine/exp/setprio/XCD swizzle unchanged from R18.
// ---------------------------------------------------------------------------
__launch_bounds__(512, 4)
__global__ void attn_kernel(const u16* __restrict__ Q, const u16* __restrict__ K,
                            const u16* __restrict__ Vt, u16* __restrict__ O) {
    __shared__ __attribute__((aligned(16))) u16 SMEM[32768];  // 64 KB
    u16* Ks = SMEM;             // [256 keys][64 d], source-swizzled chunks
    u16* Vs = SMEM + 16384;     // [64 d][256 keys], source-swizzled chunks

    const int tid = threadIdx.x;
    const int w = tid >> 6;           // 8 waves
    const int lane = tid & 63;
    const int lrow = lane & 15, lquad = lane >> 4;
    const int qg = w & 3;             // q-group pair: groups qg, qg+4
    const int kh = w >> 2;            // key half: 0 -> keys [0,128), 1 -> [128,256)

    // XCD-chunked bijective block map: XCD x owns bh = 4x..4x+3, 16 q-tiles each
    const int L = blockIdx.y * 16 + blockIdx.x;      // dispatch-linear 0..511
    const int xcd = L & 7, off = L >> 3;             // off 0..63
    const int bh = xcd * 4 + (off >> 4);             // 0..31
    const int q0 = (off & 15) * 128;

    const size_t base = (size_t)bh * SEQ * HDIM;
    const u16* Qg = Q + base;
    const u16* Kg = K + base;
    const u16* Vg = Vt + base;  // [d][s]

    // Q as B-operand of 16x16x32: lane holds q = lrow, d = kc*32 + lquad*8 + j
    frag_ab qf[2][2];   // [group g][kc]
    #pragma unroll
    for (int g = 0; g < 2; ++g)
        #pragma unroll
        for (int kc = 0; kc < 2; ++kc)
            qf[g][kc] = *(const frag_ab*)&Qg[(size_t)(q0 + (qg + g * 4) * 16 + lrow) * HDIM + kc * 32 + lquad * 8];

    frag_cd accOT[2][4];   // [group][df]: partial O^T, lane q = lrow, d = df*16+lquad*4+i
    #pragma unroll
    for (int g = 0; g < 2; ++g)
        #pragma unroll
        for (int df = 0; df < 4; df++) accOT[g][df] = (frag_cd){0.f, 0.f, 0.f, 0.f};
    f32x2 la0 = (f32x2){0.f, 0.f}, la1 = (f32x2){0.f, 0.f};  // packed rowsum partials

    // ---- hoisted staging addresses (kt-invariant except constant stride) ----
    // K tile 256x64 = 2048 chunks: rk=c>>3 (256), ck=c&7; src chunk = ck^(rk&7)
    // V tile 64x256 = 2048 chunks: rv=c>>5 (64), gv=c&31; src chunk = gv^(rv&7)
    const u16* gk[4]; const u16* gv[4]; char* lk[4]; char* lv[4];
    #pragma unroll
    for (int i = 0; i < 4; ++i) {
        const int c = i * 512 + tid;
        gk[i] = Kg + ((c >> 3) * HDIM + (((c & 7) ^ ((c >> 3) & 7)) << 3));
        gv[i] = Vg + ((size_t)(c >> 5) * SEQ + (((c & 31) ^ ((c >> 5) & 7)) << 3));
        lk[i] = (char*)Ks + (i * 512 + w * 64) * 16;   // + implicit lane*16
        lv[i] = (char*)Vs + (i * 512 + w * 64) * 16;
    }

    // ---- hoisted LDS fragment base pointers (kt-invariant) ----
    // QK A-rows interleaved: sub0 row = kh*128 + 8*(lrow>>2) + (lrow&3);
    // sub1 row = +4. (row&7 = lrow&3 resp. lrow&3+4 -> bake into XOR.)
    const int rA = kh * 128 + 8 * (lrow >> 2) + (lrow & 3);
    const int rB = rA + 4;
    const u16* kA0 = Ks + rA * 64 + (((0 + lquad) ^ (lrow & 3)) << 3);
    const u16* kA1 = Ks + rA * 64 + (((4 + lquad) ^ (lrow & 3)) << 3);
    const u16* kB0 = Ks + rB * 64 + (((0 + lquad) ^ ((lrow & 3) + 4)) << 3);
    const u16* kB1 = Ks + rB * 64 + (((4 + lquad) ^ ((lrow & 3) + 4)) << 3);
    // PV V-operand (A of 16x16x32): row d = lrow (+df*16), k-chunk = pair*4+lquad
    const u16* vb[4];
    #pragma unroll
    for (int pr = 0; pr < 4; ++pr) {
        const int gc = kh * 16 + pr * 4 + lquad;   // 16B chunk index within V row
        vb[pr] = Vs + lrow * 256 + ((gc ^ (lrow & 7)) << 3);
    }

    for (int kt = 0; kt < SEQ / 256; ++kt) {
        __syncthreads();   // all reads of SMEM done
        #pragma unroll
        for (int i = 0; i < 4; ++i) {
            __builtin_amdgcn_global_load_lds((const __attribute__((address_space(1))) void*)gk[i],
                                             (__attribute__((address_space(3))) void*)lk[i], 16, 0, 0);
            __builtin_amdgcn_global_load_lds((const __attribute__((address_space(1))) void*)gv[i],
                                             (__attribute__((address_space(3))) void*)lv[i], 16, 0, 0);
            gk[i] += 256 * HDIM;   // next 256-key tile
            gv[i] += 256;
        }
        __syncthreads();   // drain vmcnt, tile visible

        // this wave's 128 keys in 4 pairs of 32; P feeds PV at K=32 directly
        #pragma unroll
        for (int pr = 0; pr < 4; ++pr) {
            frag_cd sA0 = (frag_cd){0.f, 0.f, 0.f, 0.f};   // sub0, group0: keys 8lq+0..3
            frag_cd sA1 = (frag_cd){0.f, 0.f, 0.f, 0.f};   // sub0, group1
            frag_cd sB0 = (frag_cd){0.f, 0.f, 0.f, 0.f};   // sub1, group0: keys 8lq+4..7
            frag_cd sB1 = (frag_cd){0.f, 0.f, 0.f, 0.f};   // sub1, group1
            __builtin_amdgcn_s_setprio(1);
            {
                frag_ab f0 = *(const frag_ab*)(kA0 + pr * 2048);
                frag_ab f1 = *(const frag_ab*)(kA1 + pr * 2048);
                sA0 = __builtin_amdgcn_mfma_f32_16x16x32_bf16(f0, qf[0][0], sA0, 0, 0, 0);
                sA1 = __builtin_amdgcn_mfma_f32_16x16x32_bf16(f0, qf[1][0], sA1, 0, 0, 0);
                sA0 = __builtin_amdgcn_mfma_f32_16x16x32_bf16(f1, qf[0][1], sA0, 0, 0, 0);
                sA1 = __builtin_amdgcn_mfma_f32_16x16x32_bf16(f1, qf[1][1], sA1, 0, 0, 0);
                frag_ab g0 = *(const frag_ab*)(kB0 + pr * 2048);
                frag_ab g1 = *(const frag_ab*)(kB1 + pr * 2048);
                sB0 = __builtin_amdgcn_mfma_f32_16x16x32_bf16(g0, qf[0][0], sB0, 0, 0, 0);
                sB1 = __builtin_amdgcn_mfma_f32_16x16x32_bf16(g0, qf[1][0], sB1, 0, 0, 0);
                sB0 = __builtin_amdgcn_mfma_f32_16x16x32_bf16(g1, qf[0][1], sB0, 0, 0, 0);
                sB1 = __builtin_amdgcn_mfma_f32_16x16x32_bf16(g1, qf[1][1], sB1, 0, 0, 0);
            }
            __builtin_amdgcn_s_setprio(0);

            // exp + pack: pb[g] holds keys 8*lquad + j (j=0..7) as bf16
            frag_ab pb0, pb1;
            {
                float e0 = fexp2(sA0[0]), e1 = fexp2(sA0[1]);
                float e2 = fexp2(sA0[2]), e3 = fexp2(sA0[3]);
                float e4 = fexp2(sB0[0]), e5 = fexp2(sB0[1]);
                float e6 = fexp2(sB0[2]), e7 = fexp2(sB0[3]);
                f32x2 a = {e0, e1}, b2 = {e2, e3}, c2 = {e4, e5}, d2 = {e6, e7};
                la0 += (a + b2) + (c2 + d2);
                union { frag_ab s; unsigned int u[4]; } pu;
                pu.u[0] = pkrn(e0, e1); pu.u[1] = pkrn(e2, e3);
                pu.u[2] = pkrn(e4, e5); pu.u[3] = pkrn(e6, e7);
                pb0 = pu.s;
            }
            {
                float e0 = fexp2(sA1[0]), e1 = fexp2(sA1[1]);
                float e2 = fexp2(sA1[2]), e3 = fexp2(sA1[3]);
                float e4 = fexp2(sB1[0]), e5 = fexp2(sB1[1]);
                float e6 = fexp2(sB1[2]), e7 = fexp2(sB1[3]);
                f32x2 a = {e0, e1}, b2 = {e2, e3}, c2 = {e4, e5}, d2 = {e6, e7};
                la1 += (a + b2) + (c2 + d2);
                union { frag_ab s; unsigned int u[4]; } pu;
                pu.u[0] = pkrn(e0, e1); pu.u[1] = pkrn(e2, e3);
                pu.u[2] = pkrn(e4, e5); pu.u[3] = pkrn(e6, e7);
                pb1 = pu.s;
            }

            // O^T += V^T . P^T at K=32: each V b128 fragment feeds both q-groups
            __builtin_amdgcn_s_setprio(1);
            {
                const u16* vp = vb[pr];
                #pragma unroll
                for (int df = 0; df < 4; df++) {
                    frag_ab vf = *(const frag_ab*)(vp + df * 16 * 256);
                    accOT[0][df] = __builtin_amdgcn_mfma_f32_16x16x32_bf16(vf, pb0, accOT[0][df], 0, 0, 0);
                    accOT[1][df] = __builtin_amdgcn_mfma_f32_16x16x32_bf16(vf, pb1, accOT[1][df], 0, 0, 0);
                }
            }
            __builtin_amdgcn_s_setprio(0);
        }
    }

    // rowsums: pack-halves + quad reduce (lanes lrow, +16, +32, +48 hold same q)
    float s0 = la0[0] + la0[1];
    s0 += __shfl_xor(s0, 16);
    s0 += __shfl_xor(s0, 32);
    float s1 = la1[0] + la1[1];
    s1 += __shfl_xor(s1, 16);
    s1 += __shfl_xor(s1, 32);

    // combine key-halves additively via LDS (reuse SMEM; stride 68 spreads banks)
    float* comb = (float*)SMEM;               // [128 q][68], 34816 B
    float* lsum = (float*)SMEM + 128 * 68;    // 128 f32
    __syncthreads();   // all tile reads done before overwrite
    if (kh) {
        #pragma unroll
        for (int g = 0; g < 2; ++g) {
            float* crow = comb + ((qg + g * 4) * 16 + lrow) * 68;
            #pragma unroll
            for (int df = 0; df < 4; df++)
                *(float4*)&crow[df * 16 + lquad * 4] =
                    (float4){accOT[g][df][0], accOT[g][df][1], accOT[g][df][2], accOT[g][df][3]};
        }
        if (lquad == 0) {
            lsum[qg * 16 + lrow] = s0;
            lsum[(qg + 4) * 16 + lrow] = s1;
        }
    }
    __syncthreads();
    if (!kh) {
        const int b = bh >> 4, h = bh & (NHEAD - 1);
        #pragma unroll
        for (int g = 0; g < 2; ++g) {
            const float* crow = comb + ((qg + g * 4) * 16 + lrow) * 68;
            #pragma unroll
            for (int df = 0; df < 4; df++) {
                float4 c = *(const float4*)&crow[df * 16 + lquad * 4];
                accOT[g][df][0] += c.x; accOT[g][df][1] += c.y;
                accOT[g][df][2] += c.z; accOT[g][df][3] += c.w;
            }
            float lacc = (g ? s1 : s0) + lsum[(qg + g * 4) * 16 + lrow];

            // epilogue: lane owns one q per group -> single reciprocal; b64 stores
            const int s = q0 + (qg + g * 4) * 16 + lrow;
            const float inv = 1.0f / lacc;
            u16* orow = O + ((size_t)(b * SEQ + s)) * D_MODEL + h * HDIM;
            #pragma unroll
            for (int df = 0; df < 4; df++) {
                union { unsigned int u[2]; ushort4 s4; } o;
                o.u[0] = pkrn(accOT[g][df][0] * inv, accOT[g][df][1] * inv);
                o.u[1] = pkrn(accOT[g][df][2] * inv, accOT[g][df][3] * inv);
                *(ushort4*)&orow[df * 16 + lquad * 4] = o.s4;
            }
        }
    }
}

// ---------------------------------------------------------------------------
// Workspace (u16 elems): xb [0,4M) | Wt 4 slabs [4M,8M) | Q,K [8M,16M)
//                        Vt [16M,20M) | attn-out [20M,24M)   = 48 MB
// ---------------------------------------------------------------------------
extern "C" void kernel_launch(void* const* d_in, const int* in_sizes, int n_in,
                              void* d_out, int out_size, void* d_ws, size_t ws_size,
                              hipStream_t stream) {
    const float* x  = (const float*)d_in[0];
    const float* Wq = (const float*)d_in[1];
    const float* bq = (const float*)d_in[2];
    const float* Wk = (const float*)d_in[3];
    const float* bk = (const float*)d_in[4];
    const float* Wv = (const float*)d_in[5];
    const float* bv = (const float*)d_in[6];
    const float* Wo = (const float*)d_in[7];
    const float* bo = (const float*)d_in[8];

    u16* ws = (u16*)d_ws;
    const size_t WSZ = (size_t)D_MODEL * D_MODEL;    // 1M elems
    const size_t TSZ = (size_t)MTOT * D_MODEL;       // 4M elems
    u16* xb  = ws;
    u16* Wt  = ws + 4 * WSZ;
    u16* QKw = ws + 8 * WSZ;        // Q slab 0, K slab 1
    u16* Vtw = QKw + 2 * TSZ;
    u16* Aw  = Vtw + TSZ;

    prep<<<dim3(32, 32, 5), dim3(32, 8), 0, stream>>>(Wq, Wk, Wv, Wo, x, Wt, xb);
    gemm_qkvt<<<dim3(768), 256, 0, stream>>>(xb, Wt, bq, bk, bv, QKw, Vtw);
    attn_kernel<<<dim3(16, 32), 512, 0, stream>>>(QKw, QKw + TSZ, Vtw, Aw);
    gemm_out<<<dim3(16, 64), 256, 0, stream>>>(Aw, Wt + 3 * WSZ, bo, (float*)d_out);
}

// Round 13
// 192.948 us; speedup vs baseline: 1.0425x; 1.0203x over previous
//
#include <hip/hip_runtime.h>
#include <hip/hip_bf16.h>

// MultiBertAttention fp32 I/O, bf16 MFMA internals.
// R22 = R21 resubmit (previous round died in GPU acquisition before running).
// R21: attn 1-deep software pipeline (T15). The wave's in-order chain
//      QK(pr)->exp(pr)->PV(pr) stalled at each dependency; reorder to
//      QK(pr) -> PV(pr-1) -> exp/pack(pr) so every consumer has ~16
//      independent MFMAs between it and its producer. PV(3) flushed before
//      the tile barrier (Vs reads stay in-tile). Pure program-order change:
//      staging, swizzles, layouts, kh-combine identical to verified R20.
//      prep / gemm_qkvt / gemm_out unchanged.

typedef unsigned short u16;

#define D_MODEL 1024
#define NHEAD 16
#define HDIM 64
#define BATCH 2
#define SEQ 2048
#define MTOT (BATCH * SEQ)  // 4096

#define QSCALE 0.18033688011112042f  // (1/8) * log2(e)

using frag_ab = __attribute__((ext_vector_type(8))) short;  // 8 bf16 (16x16x32 A/B)
using frag_cd = __attribute__((ext_vector_type(4))) float;  // 4 fp32
using f32x2   = __attribute__((ext_vector_type(2))) float;
using u16x8   = __attribute__((ext_vector_type(8))) unsigned short;

__device__ __forceinline__ u16 f2u(float f) {  // RNE fp32->bf16
    union { float f; unsigned int i; } x;
    x.f = f;
    unsigned int r = x.i + 0x7fffu + ((x.i >> 16) & 1u);
    return (u16)(r >> 16);
}
__device__ __forceinline__ unsigned int pkrn(float a, float b) {  // v_cvt_pk_bf16_f32
    union { __hip_bfloat162 h; unsigned int u; } c;
    c.h = __float22bfloat162_rn(float2{a, b});
    return c.u;
}
__device__ __forceinline__ float fexp2(float x) {  // raw v_exp_f32 (inputs bounded)
#if __has_builtin(__builtin_amdgcn_exp2f)
    return __builtin_amdgcn_exp2f(x);
#else
    float r;
    asm("v_exp_f32 %0, %1" : "=v"(r) : "v"(x));
    return r;
#endif
}

// ---------------------------------------------------------------------------
// prep: z<4 -> Wt[z][n][k] = bf16(W_z[k][n]); z==4 -> xb = bf16(x).
// ---------------------------------------------------------------------------
__global__ void prep(const float* __restrict__ W0, const float* __restrict__ W1,
                     const float* __restrict__ W2, const float* __restrict__ W3,
                     const float* __restrict__ X, u16* __restrict__ Wt,
                     u16* __restrict__ Xb) {
    const int z = blockIdx.z;
    const int tx = threadIdx.x, ty = threadIdx.y;
    const int tid = ty * 32 + tx;
    if (z < 4) {
        __shared__ u16 t[32][33];   // t[k_local][n_local]
        const float* W = (z == 0) ? W0 : (z == 1) ? W1 : (z == 2) ? W2 : W3;
        u16* o = Wt + (size_t)z * D_MODEL * D_MODEL;
        int n0 = blockIdx.x * 32, k0 = blockIdx.y * 32;
        #pragma unroll
        for (int i = ty; i < 32; i += 8) t[i][tx] = f2u(W[(size_t)(k0 + i) * D_MODEL + n0 + tx]);
        __syncthreads();
        const int r = tid >> 3, c = tid & 7;   // out row n = r, k-group = c
        ushort4 o4;
        o4.x = t[4 * c + 0][r]; o4.y = t[4 * c + 1][r];
        o4.z = t[4 * c + 2][r]; o4.w = t[4 * c + 3][r];
        *(ushort4*)&o[(size_t)(n0 + r) * D_MODEL + k0 + 4 * c] = o4;
    } else {
        size_t base = ((size_t)(blockIdx.y * 32 + blockIdx.x) * 256 + tid) * 16;
        #pragma unroll
        for (int c = 0; c < 4; ++c) {
            float4 v = *(const float4*)&X[base + c * 4];
            ushort4 o;
            o.x = f2u(v.x); o.y = f2u(v.y); o.z = f2u(v.z); o.w = f2u(v.w);
            *(ushort4*)&Xb[base + c * 4] = o;
        }
    }
}

// ---------------------------------------------------------------------------
// Fused QKV + V^T GEMM, 768 blocks (1D). 128x128 tile, BK=64, global_load_lds.
// XCD swizzle bid=(b&7)*96+(b>>3). 4 blocks/CU. Epilogue: C staged to
// LDS [128][136], then 8x ushort8 coalesced stores per thread.
// ---------------------------------------------------------------------------
__launch_bounds__(256, 4)
__global__ void gemm_qkvt(const u16* __restrict__ xb, const u16* __restrict__ Wt,
                          const float* __restrict__ bq, const float* __restrict__ bk,
                          const float* __restrict__ bv, u16* __restrict__ QKw,
                          u16* __restrict__ Vtw) {
    constexpr int BK = 64;
    __shared__ __attribute__((aligned(16))) u16 SM[128 * 136];  // 34.8 KB
    u16* As = SM;              // [128][64]
    u16* Bs = SM + 128 * BK;   // [128][64]

    const int tid = threadIdx.x;
    const int w = tid >> 6;
    const int lane = tid & 63;
    const int lrow = lane & 15, lquad = lane >> 4;
    const size_t WSZ = (size_t)D_MODEL * D_MODEL;
    const size_t TSZ = (size_t)MTOT * D_MODEL;

    const int bid0 = blockIdx.x;
    const int bid = (bid0 & 7) * 96 + (bid0 >> 3);   // XCD-chunked, bijective on 768
    const bool vt = bid >= 512;
    const int z = vt ? 2 : (bid >> 8);
    const int t = vt ? (bid - 512) : (bid & 255);
    const int n0 = vt ? (t & 31) * 128 : (t & 7) * 128;
    const int m0 = vt ? (t >> 5) * 128 : (t >> 3) * 128;
    const u16* Ap = vt ? (Wt + 2 * WSZ) : xb;
    const u16* Bp = vt ? xb : (Wt + (size_t)z * WSZ);
    const float* bias = vt ? bv : (z ? bk : bq);

    frag_cd acc[4][4];
    #pragma unroll
    for (int i = 0; i < 4; i++)
        #pragma unroll
        for (int j = 0; j < 4; j++) acc[i][j] = (frag_cd){0.f, 0.f, 0.f, 0.f};

    const int wm = (w >> 1) * 64, wn = (w & 1) * 64;

    for (int k0 = 0; k0 < D_MODEL; k0 += BK) {
        __syncthreads();
        #pragma unroll
        for (int it = 0; it < 4; ++it) {
            int c = it * 256 + tid;
            int r = c >> 3, c8 = c & 7;
            const u16* ga = Ap + (size_t)(m0 + r) * D_MODEL + k0 + c8 * 8;
            char* la = (char*)As + (it * 256 + w * 64) * 16;
            __builtin_amdgcn_global_load_lds((const __attribute__((address_space(1))) void*)ga,
                                             (__attribute__((address_space(3))) void*)la, 16, 0, 0);
            const u16* gb = Bp + (size_t)(n0 + r) * D_MODEL + k0 + c8 * 8;
            char* lb = (char*)Bs + (it * 256 + w * 64) * 16;
            __builtin_amdgcn_global_load_lds((const __attribute__((address_space(1))) void*)gb,
                                             (__attribute__((address_space(3))) void*)lb, 16, 0, 0);
        }
        __syncthreads();

        #pragma unroll
        for (int kc = 0; kc < 2; ++kc) {
            frag_ab av[4], bvv[4];
            #pragma unroll
            for (int i = 0; i < 4; i++)
                av[i] = *(const frag_ab*)&As[(wm + i * 16 + lrow) * BK + kc * 32 + lquad * 8];
            #pragma unroll
            for (int j = 0; j < 4; j++)
                bvv[j] = *(const frag_ab*)&Bs[(wn + j * 16 + lrow) * BK + kc * 32 + lquad * 8];
            #pragma unroll
            for (int i = 0; i < 4; i++)
                #pragma unroll
                for (int j = 0; j < 4; j++)
                    acc[i][j] = __builtin_amdgcn_mfma_f32_16x16x32_bf16(av[i], bvv[j], acc[i][j], 0, 0, 0);
        }
    }

    // ---- epilogue: stage to LDS [128][136], then coalesced ushort8 stores ----
    const float scale = (!vt && z == 0) ? QSCALE : 1.0f;
    __syncthreads();   // all MFMA reads of As/Bs done before overwrite
    #pragma unroll
    for (int j = 0; j < 4; j++) {
        int col = wn + j * 16 + lrow;
        float bn = vt ? 0.f : bias[n0 + col];
        #pragma unroll
        for (int i = 0; i < 4; i++) {
            #pragma unroll
            for (int rr = 0; rr < 4; ++rr) {
                int row = wm + i * 16 + lquad * 4 + rr;
                float v = vt ? (acc[i][j][rr] + bias[m0 + row])
                             : (acc[i][j][rr] + bn) * scale;
                SM[row * 136 + col] = f2u(v);
            }
        }
    }
    __syncthreads();
    #pragma unroll
    for (int it = 0; it < 8; ++it) {
        int idx = it * 256 + tid;          // 0..2047
        int row = idx >> 4, seg = idx & 15;
        u16x8 v8 = *(const u16x8*)&SM[row * 136 + seg * 8];
        if (!vt) {
            int gm = m0 + row;             // b, s
            int gc = n0 + seg * 8;         // h, d0
            int b = gm >> 11, s = gm & (SEQ - 1);
            int h = gc >> 6, d0 = gc & (HDIM - 1);
            u16* oz = QKw + (size_t)z * TSZ;
            *(u16x8*)&oz[(((size_t)(b * NHEAD + h)) * SEQ + s) * HDIM + d0] = v8;
        } else {
            int gm = m0 + row;             // h, d
            int h = gm >> 6, d = gm & (HDIM - 1);
            int gc = n0 + seg * 8;         // b, s0
            int b = gc >> 11, s0 = gc & (SEQ - 1);
            *(u16x8*)&Vtw[(((size_t)(b * NHEAD + h)) * HDIM + d) * SEQ + s0] = v8;
        }
    }
}

// ---------------------------------------------------------------------------
// Out projection (R17): 64x64 tile, grid 1024 = 4/CU, LDS 17.4KB.
// ---------------------------------------------------------------------------
__launch_bounds__(256, 4)
__global__ void gemm_out(const u16* __restrict__ A, const u16* __restrict__ Wt,
                         const float* __restrict__ bias, float* __restrict__ out) {
    constexpr int BK = 64;
    __shared__ __attribute__((aligned(16))) u16 SM[64 * 68 * 2];  // 17408 B
    u16* As = SM;             // [64][64]
    u16* Bs = SM + 64 * BK;   // [64][64]

    const int tid = threadIdx.x;
    const int w = tid >> 6;
    const int lane = tid & 63;
    const int lrow = lane & 15, lquad = lane >> 4;
    const int L0 = blockIdx.y * 16 + blockIdx.x;     // dispatch-linear 0..1023
    const int L = (L0 & 7) * 128 + (L0 >> 3);        // XCD-chunked, bijective on 1024
    const int m0 = (L >> 4) * 64, n0 = (L & 15) * 64;

    frag_cd acc[2][2];
    #pragma unroll
    for (int i = 0; i < 2; i++)
        #pragma unroll
        for (int j = 0; j < 2; j++) acc[i][j] = (frag_cd){0.f, 0.f, 0.f, 0.f};

    const int wm = (w >> 1) * 32, wn = (w & 1) * 32;

    for (int k0 = 0; k0 < D_MODEL; k0 += BK) {
        __syncthreads();
        #pragma unroll
        for (int it = 0; it < 2; ++it) {
            int c = it * 256 + tid;
            int r = c >> 3, c8 = c & 7;
            const u16* ga = A + (size_t)(m0 + r) * D_MODEL + k0 + c8 * 8;
            char* la = (char*)As + (it * 256 + w * 64) * 16;
            __builtin_amdgcn_global_load_lds((const __attribute__((address_space(1))) void*)ga,
                                             (__attribute__((address_space(3))) void*)la, 16, 0, 0);
            const u16* gb = Wt + (size_t)(n0 + r) * D_MODEL + k0 + c8 * 8;
            char* lb = (char*)Bs + (it * 256 + w * 64) * 16;
            __builtin_amdgcn_global_load_lds((const __attribute__((address_space(1))) void*)gb,
                                             (__attribute__((address_space(3))) void*)lb, 16, 0, 0);
        }
        __syncthreads();

        #pragma unroll
        for (int kc = 0; kc < 2; ++kc) {
            frag_ab av[2], bvv[2];
            #pragma unroll
            for (int i = 0; i < 2; i++)
                av[i] = *(const frag_ab*)&As[(wm + i * 16 + lrow) * BK + kc * 32 + lquad * 8];
            #pragma unroll
            for (int j = 0; j < 2; j++)
                bvv[j] = *(const frag_ab*)&Bs[(wn + j * 16 + lrow) * BK + kc * 32 + lquad * 8];
            #pragma unroll
            for (int i = 0; i < 2; i++)
                #pragma unroll
                for (int j = 0; j < 2; j++)
                    acc[i][j] = __builtin_amdgcn_mfma_f32_16x16x32_bf16(av[i], bvv[j], acc[i][j], 0, 0, 0);
        }
    }

    // ---- epilogue: stage f32 to LDS [64][68], then coalesced float4 stores ----
    float* Tf = (float*)SM;
    __syncthreads();   // all MFMA reads done before overwrite
    #pragma unroll
    for (int j = 0; j < 2; j++) {
        int col = wn + j * 16 + lrow;
        float bvf = bias[n0 + col];
        #pragma unroll
        for (int i = 0; i < 2; i++)
            #pragma unroll
            for (int rr = 0; rr < 4; ++rr) {
                int row = wm + i * 16 + lquad * 4 + rr;
                Tf[row * 68 + col] = acc[i][j][rr] + bvf;
            }
    }
    __syncthreads();
    #pragma unroll
    for (int it = 0; it < 4; ++it) {
        int idx = it * 256 + tid;          // 0..1023
        int row = idx >> 4, seg = idx & 15;
        float4 v = *(const float4*)&Tf[row * 68 + seg * 4];
        *(float4*)&out[(size_t)(m0 + row) * D_MODEL + n0 + seg * 4] = v;
    }
}

// ---------------------------------------------------------------------------
// Attention, R21: 256-key tiles, PV at K=32, 1-deep software pipeline.
// Grid (16,32) = 512 blocks (2/CU), 512 thr = 8 waves (4 qg x 2 kh).
// Per pr: issue QK(pr) MFMAs -> PV(pr-1) (P ready) -> exp/pack(pr).
// PV(3) flushed before the tile barrier. Layouts identical to R20.
// ---------------------------------------------------------------------------
__launch_bounds__(512, 4)
__global__ void attn_kernel(const u16* __restrict__ Q, const u16* __restrict__ K,
                            const u16* __restrict__ Vt, u16* __restrict__ O) {
    __shared__ __attribute__((aligned(16))) u16 SMEM[32768];  // 64 KB
    u16* Ks = SMEM;             // [256 keys][64 d], source-swizzled chunks
    u16* Vs = SMEM + 16384;     // [64 d][256 keys], source-swizzled chunks

    const int tid = threadIdx.x;
    const int w = tid >> 6;           // 8 waves
    const int lane = tid & 63;
    const int lrow = lane & 15, lquad = lane >> 4;
    const int qg = w & 3;             // q-group pair: groups qg, qg+4
    const int kh = w >> 2;            // key half: 0 -> keys [0,128), 1 -> [128,256)

    // XCD-chunked bijective block map: XCD x owns bh = 4x..4x+3, 16 q-tiles each
    const int L = blockIdx.y * 16 + blockIdx.x;      // dispatch-linear 0..511
    const int xcd = L & 7, off = L >> 3;             // off 0..63
    const int bh = xcd * 4 + (off >> 4);             // 0..31
    const int q0 = (off & 15) * 128;

    const size_t base = (size_t)bh * SEQ * HDIM;
    const u16* Qg = Q + base;
    const u16* Kg = K + base;
    const u16* Vg = Vt + base;  // [d][s]

    // Q as B-operand of 16x16x32: lane holds q = lrow, d = kc*32 + lquad*8 + j
    frag_ab qf[2][2];   // [group g][kc]
    #pragma unroll
    for (int g = 0; g < 2; ++g)
        #pragma unroll
        for (int kc = 0; kc < 2; ++kc)
            qf[g][kc] = *(const frag_ab*)&Qg[(size_t)(q0 + (qg + g * 4) * 16 + lrow) * HDIM + kc * 32 + lquad * 8];

    frag_cd accOT[2][4];   // [group][df]: partial O^T, lane q = lrow, d = df*16+lquad*4+i
    #pragma unroll
    for (int g = 0; g < 2; ++g)
        #pragma unroll
        for (int df = 0; df < 4; df++) accOT[g][df] = (frag_cd){0.f, 0.f, 0.f, 0.f};
    f32x2 la0 = (f32x2){0.f, 0.f}, la1 = (f32x2){0.f, 0.f};  // packed rowsum partials

    // ---- hoisted staging addresses (kt-invariant except constant stride) ----
    // K tile 256x64 = 2048 chunks: rk=c>>3 (256), ck=c&7; src chunk = ck^(rk&7)
    // V tile 64x256 = 2048 chunks: rv=c>>5 (64), gv=c&31; src chunk = gv^(rv&7)
    const u16* gk[4]; const u16* gv[4]; char* lk[4]; char* lv[4];
    #pragma unroll
    for (int i = 0; i < 4; ++i) {
        const int c = i * 512 + tid;
        gk[i] = Kg + ((c >> 3) * HDIM + (((c & 7) ^ ((c >> 3) & 7)) << 3));
        gv[i] = Vg + ((size_t)(c >> 5) * SEQ + (((c & 31) ^ ((c >> 5) & 7)) << 3));
        lk[i] = (char*)Ks + (i * 512 + w * 64) * 16;   // + implicit lane*16
        lv[i] = (char*)Vs + (i * 512 + w * 64) * 16;
    }

    // ---- hoisted LDS fragment base pointers (kt-invariant) ----
    // QK A-rows interleaved: sub0 row = kh*128 + 8*(lrow>>2) + (lrow&3);
    // sub1 row = +4. (row&7 = lrow&3 resp. lrow&3+4 -> bake into XOR.)
    const int rA = kh * 128 + 8 * (lrow >> 2) + (lrow & 3);
    const int rB = rA + 4;
    const u16* kA0 = Ks + rA * 64 + (((0 + lquad) ^ (lrow & 3)) << 3);
    const u16* kA1 = Ks + rA * 64 + (((4 + lquad) ^ (lrow & 3)) << 3);
    const u16* kB0 = Ks + rB * 64 + (((0 + lquad) ^ ((lrow & 3) + 4)) << 3);
    const u16* kB1 = Ks + rB * 64 + (((4 + lquad) ^ ((lrow & 3) + 4)) << 3);
    // PV V-operand (A of 16x16x32): row d = lrow (+df*16), k-chunk = pair*4+lquad
    const u16* vb[4];
    #pragma unroll
    for (int pr = 0; pr < 4; ++pr) {
        const int gc = kh * 16 + pr * 4 + lquad;   // 16B chunk index within V row
        vb[pr] = Vs + lrow * 256 + ((gc ^ (lrow & 7)) << 3);
    }

    for (int kt = 0; kt < SEQ / 256; ++kt) {
        __syncthreads();   // all reads of SMEM done
        #pragma unroll
        for (int i = 0; i < 4; ++i) {
            __builtin_amdgcn_global_load_lds((const __attribute__((address_space(1))) void*)gk[i],
                                             (__attribute__((address_space(3))) void*)lk[i], 16, 0, 0);
            __builtin_amdgcn_global_load_lds((const __attribute__((address_space(1))) void*)gv[i],
                                             (__attribute__((address_space(3))) void*)lv[i], 16, 0, 0);
            gk[i] += 256 * HDIM;   // next 256-key tile
            gv[i] += 256;
        }
        __syncthreads();   // drain vmcnt, tile visible

        // 1-deep pipeline over 4 prs: QK(pr) || PV(pr-1) || exp(pr)
        frag_ab pbp0, pbp1;   // previous pr's packed P
        #pragma unroll
        for (int pr = 0; pr < 4; ++pr) {
            frag_cd sA0 = (frag_cd){0.f, 0.f, 0.f, 0.f};   // sub0, group0: keys 8lq+0..3
            frag_cd sA1 = (frag_cd){0.f, 0.f, 0.f, 0.f};   // sub0, group1
            frag_cd sB0 = (frag_cd){0.f, 0.f, 0.f, 0.f};   // sub1, group0: keys 8lq+4..7
            frag_cd sB1 = (frag_cd){0.f, 0.f, 0.f, 0.f};   // sub1, group1
            __builtin_amdgcn_s_setprio(1);
            {
                frag_ab f0 = *(const frag_ab*)(kA0 + pr * 2048);
                frag_ab f1 = *(const frag_ab*)(kA1 + pr * 2048);
                sA0 = __builtin_amdgcn_mfma_f32_16x16x32_bf16(f0, qf[0][0], sA0, 0, 0, 0);
                sA1 = __builtin_amdgcn_mfma_f32_16x16x32_bf16(f0, qf[1][0], sA1, 0, 0, 0);
                sA0 = __builtin_amdgcn_mfma_f32_16x16x32_bf16(f1, qf[0][1], sA0, 0, 0, 0);
                sA1 = __builtin_amdgcn_mfma_f32_16x16x32_bf16(f1, qf[1][1], sA1, 0, 0, 0);
                frag_ab g0 = *(const frag_ab*)(kB0 + pr * 2048);
                frag_ab g1 = *(const frag_ab*)(kB1 + pr * 2048);
                sB0 = __builtin_amdgcn_mfma_f32_16x16x32_bf16(g0, qf[0][0], sB0, 0, 0, 0);
                sB1 = __builtin_amdgcn_mfma_f32_16x16x32_bf16(g0, qf[1][0], sB1, 0, 0, 0);
                sB0 = __builtin_amdgcn_mfma_f32_16x16x32_bf16(g1, qf[0][1], sB0, 0, 0, 0);
                sB1 = __builtin_amdgcn_mfma_f32_16x16x32_bf16(g1, qf[1][1], sB1, 0, 0, 0);
            }
            // PV(pr-1): P from previous pr is ready; hides QK(pr) latency
            if (pr > 0) {
                const u16* vp = vb[pr - 1];
                #pragma unroll
                for (int df = 0; df < 4; df++) {
                    frag_ab vf = *(const frag_ab*)(vp + df * 4096);
                    accOT[0][df] = __builtin_amdgcn_mfma_f32_16x16x32_bf16(vf, pbp0, accOT[0][df], 0, 0, 0);
                    accOT[1][df] = __builtin_amdgcn_mfma_f32_16x16x32_bf16(vf, pbp1, accOT[1][df], 0, 0, 0);
                }
            }
            __builtin_amdgcn_s_setprio(0);

            // exp + pack(pr): QK(pr) results are ~16 MFMAs old by now
            {
                float e0 = fexp2(sA0[0]), e1 = fexp2(sA0[1]);
                float e2 = fexp2(sA0[2]), e3 = fexp2(sA0[3]);
                float e4 = fexp2(sB0[0]), e5 = fexp2(sB0[1]);
                float e6 = fexp2(sB0[2]), e7 = fexp2(sB0[3]);
                f32x2 a = {e0, e1}, b2 = {e2, e3}, c2 = {e4, e5}, d2 = {e6, e7};
                la0 += (a + b2) + (c2 + d2);
                union { frag_ab s; unsigned int u[4]; } pu;
                pu.u[0] = pkrn(e0, e1); pu.u[1] = pkrn(e2, e3);
                pu.u[2] = pkrn(e4, e5); pu.u[3] = pkrn(e6, e7);
                pbp0 = pu.s;
            }
            {
                float e0 = fexp2(sA1[0]), e1 = fexp2(sA1[1]);
                float e2 = fexp2(sA1[2]), e3 = fexp2(sA1[3]);
                float e4 = fexp2(sB1[0]), e5 = fexp2(sB1[1]);
                float e6 = fexp2(sB1[2]), e7 = fexp2(sB1[3]);
                f32x2 a = {e0, e1}, b2 = {e2, e3}, c2 = {e4, e5}, d2 = {e6, e7};
                la1 += (a + b2) + (c2 + d2);
                union { frag_ab s; unsigned int u[4]; } pu;
                pu.u[0] = pkrn(e0, e1); pu.u[1] = pkrn(e2, e3);
                pu.u[2] = pkrn(e4, e5); pu.u[3] = pkrn(e6, e7);
                pbp1 = pu.s;
            }
        }

        // flush PV(3) before the tile barrier (Vs reads must stay in-tile)
        __builtin_amdgcn_s_setprio(1);
        {
            const u16* vp = vb[3];
            #pragma unroll
            for (int df = 0; df < 4; df++) {
                frag_ab vf = *(const frag_ab*)(vp + df * 4096);
                accOT[0][df] = __builtin_amdgcn_mfma_f32_16x16x32_bf16(vf, pbp0, accOT[0][df], 0, 0, 0);
                accOT[1][df] = __builtin_amdgcn_mfma_f32_16x16x32_bf16(vf, pbp1, accOT[1][df], 0, 0, 0);
            }
        }
        __builtin_amdgcn_s_setprio(0);
    }

    // rowsums: pack-halves + quad reduce (lanes lrow, +16, +32, +48 hold same q)
    float s0 = la0[0] + la0[1];
    s0 += __shfl_xor(s0, 16);
    s0 += __shfl_xor(s0, 32);
    float s1 = la1[0] + la1[1];
    s1 += __shfl_xor(s1, 16);
    s1 += __shfl_xor(s1, 32);

    // combine key-halves additively via LDS (reuse SMEM; stride 68 spreads banks)
    float* comb = (float*)SMEM;               // [128 q][68], 34816 B
    float* lsum = (float*)SMEM + 128 * 68;    // 128 f32
    __syncthreads();   // all tile reads done before overwrite
    if (kh) {
        #pragma unroll
        for (int g = 0; g < 2; ++g) {
            float* crow = comb + ((qg + g * 4) * 16 + lrow) * 68;
            #pragma unroll
            for (int df = 0; df < 4; df++)
                *(float4*)&crow[df * 16 + lquad * 4] =
                    (float4){accOT[g][df][0], accOT[g][df][1], accOT[g][df][2], accOT[g][df][3]};
        }
        if (lquad == 0) {
            lsum[qg * 16 + lrow] = s0;
            lsum[(qg + 4) * 16 + lrow] = s1;
        }
    }
    __syncthreads();
    if (!kh) {
        const int b = bh >> 4, h = bh & (NHEAD - 1);
        #pragma unroll
        for (int g = 0; g < 2; ++g) {
            const float* crow = comb + ((qg + g * 4) * 16 + lrow) * 68;
            #pragma unroll
            for (int df = 0; df < 4; df++) {
                float4 c = *(const float4*)&crow[df * 16 + lquad * 4];
                accOT[g][df][0] += c.x; accOT[g][df][1] += c.y;
                accOT[g][df][2] += c.z; accOT[g][df][3] += c.w;
            }
            float lacc = (g ? s1 : s0) + lsum[(qg + g * 4) * 16 + lrow];

            // epilogue: lane owns one q per group -> single reciprocal; b64 stores
            const int s = q0 + (qg + g * 4) * 16 + lrow;
            const float inv = 1.0f / lacc;
            u16* orow = O + ((size_t)(b * SEQ + s)) * D_MODEL + h * HDIM;
            #pragma unroll
            for (int df = 0; df < 4; df++) {
                union { unsigned int u[2]; ushort4 s4; } o;
                o.u[0] = pkrn(accOT[g][df][0] * inv, accOT[g][df][1] * inv);
                o.u[1] = pkrn(accOT[g][df][2] * inv, accOT[g][df][3] * inv);
                *(ushort4*)&orow[df * 16 + lquad * 4] = o.s4;
            }
        }
    }
}

// ---------------------------------------------------------------------------
// Workspace (u16 elems): xb [0,4M) | Wt 4 slabs [4M,8M) | Q,K [8M,16M)
//                        Vt [16M,20M) | attn-out [20M,24M)   = 48 MB
// ---------------------------------------------------------------------------
extern "C" void kernel_launch(void* const* d_in, const int* in_sizes, int n_in,
                              void* d_out, int out_size, void* d_ws, size_t ws_size,
                              hipStream_t stream) {
    const float* x  = (const float*)d_in[0];
    const float* Wq = (const float*)d_in[1];
    const float* bq = (const float*)d_in[2];
    const float* Wk = (const float*)d_in[3];
    const float* bk = (const float*)d_in[4];
    const float* Wv = (const float*)d_in[5];
    const float* bv = (const float*)d_in[6];
    const float* Wo = (const float*)d_in[7];
    const float* bo = (const float*)d_in[8];

    u16* ws = (u16*)d_ws;
    const size_t WSZ = (size_t)D_MODEL * D_MODEL;    // 1M elems
    const size_t TSZ = (size_t)MTOT * D_MODEL;       // 4M elems
    u16* xb  = ws;
    u16* Wt  = ws + 4 * WSZ;
    u16* QKw = ws + 8 * WSZ;        // Q slab 0, K slab 1
    u16* Vtw = QKw + 2 * TSZ;
    u16* Aw  = Vtw + TSZ;

    prep<<<dim3(32, 32, 5), dim3(32, 8), 0, stream>>>(Wq, Wk, Wv, Wo, x, Wt, xb);
    gemm_qkvt<<<dim3(768), 256, 0, stream>>>(xb, Wt, bq, bk, bv, QKw, Vtw);
    attn_kernel<<<dim3(16, 32), 512, 0, stream>>>(QKw, QKw + TSZ, Vtw, Aw);
    gemm_out<<<dim3(16, 64), 256, 0, stream>>>(Aw, Wt + 3 * WSZ, bo, (float*)d_out);
}